// Round 1
// baseline (329.624 us; speedup 1.0000x reference)
//
#include <hip/hip_runtime.h>
#include <hip/hip_bf16.h>

#define H 256
#define Wd 256
#define H2 128

typedef unsigned short ushort_t;

__device__ __forceinline__ float mishf(float v){
  // mish(x) = x*tanh(softplus(x)) = x*(t^2-1)/(t^2+1), t=1+e^x
  //        = x * e(e+2) / (e(e+2)+2)
  if (v > 15.f) return v;             // tanh(softplus(15)) == 1 to fp32
  float e = __expf(v);
  float w = e*(e+2.f);
  return v * (w / (w + 2.f));
}

__device__ __forceinline__ ushort_t f2bf(float f){
  unsigned int u = __float_as_uint(f);
  u += 0x7fffu + ((u >> 16) & 1u);     // round-to-nearest-even
  return (ushort_t)(u >> 16);
}
__device__ __forceinline__ float bf2f(ushort_t h){
  return __uint_as_float(((unsigned int)h) << 16);
}

// ---------------------------------------------------------------------------
// K1: bottom half. f_bot = mish(conv1(x)) for rows [128,256), written directly
// into shuffled at channel-rolled position: shuffled[b, cdst*4+m, i, j],
// cdst = (c-1) mod 16  (because shuffled bottom uses bo[:, (c+1)%16]).
// ---------------------------------------------------------------------------
__global__ __launch_bounds__(256) void k1_bot(
    const float* __restrict__ x, const float* __restrict__ W1,
    const float* __restrict__ b1, ushort_t* __restrict__ shuf)
{
  int bid = blockIdx.x;          // 128 planes * 32 rowgroups
  int n   = bid >> 5;
  int rg  = bid & 31;
  int tid = threadIdx.x;
  int i   = 128 + rg*4 + (tid >> 6);   // row in [128,256)
  int j0  = (tid & 63) * 4;
  const float* xp = x + (size_t)n * (H*Wd);

  float w[4][9], bb[4];
#pragma unroll
  for (int m=0;m<4;m++){
    bb[m] = b1[m];
#pragma unroll
    for (int k=0;k<9;k++) w[m][k] = W1[m*9+k];
  }

  float xv[3][6];
#pragma unroll
  for (int r=0;r<3;r++){
    int row = i-1+r;               // >=127 always
    bool rok = (row < H);
#pragma unroll
    for (int c=0;c<6;c++){
      int col = j0-1+c;
      xv[r][c] = (rok && col>=0 && col<Wd) ? xp[row*Wd+col] : 0.f;
    }
  }

  int b = n >> 4, cs = n & 15;
  int cdst = (cs + 15) & 15;
  size_t base = ((size_t)(b*64 + cdst*4)) * (H*Wd) + (size_t)i*Wd + j0;
#pragma unroll
  for (int m=0;m<4;m++){
    float o[4];
#pragma unroll
    for (int p=0;p<4;p++){
      float s = bb[m];
#pragma unroll
      for (int ky=0;ky<3;ky++)
#pragma unroll
        for (int kx=0;kx<3;kx++)
          s = fmaf(xv[ky][p+kx], w[m][ky*3+kx], s);
      o[p] = mishf(s);
    }
    ushort4 hv;
    hv.x = f2bf(o[0]); hv.y = f2bf(o[1]); hv.z = f2bf(o[2]); hv.w = f2bf(o[3]);
    *(ushort4*)(shuf + base + (size_t)m*(H*Wd)) = hv;
  }
}

// ---------------------------------------------------------------------------
// K2: top half. Computes f_top tile in LDS (from x), g on the fly (from x_bot),
// then ti = g * (Wspan3x3 (*) f_top) + (bspan3x3 (*) f_top)  -> shuffled top.
// Tile: 16 rows x 64 cols, 256 threads, 4 px/thread.
// ---------------------------------------------------------------------------
__global__ __launch_bounds__(256) void k2_top(
    const float* __restrict__ x, const float* __restrict__ W1,
    const float* __restrict__ b1, const float* __restrict__ Wred,
    const float* __restrict__ bred, const float* __restrict__ Wspan,
    const float* __restrict__ bspan, ushort_t* __restrict__ shuf)
{
  __shared__ float xt[20][68];      // x rows itop0-2 .. itop0+17, cols j0-2..j0+65
  __shared__ float xb[18][68];      // x rows 127+itop0 .. 144+itop0, cols j0-2..j0+65
  __shared__ float ft[4][18][68];   // f rows itop0-1..itop0+16, cols j0-1..j0+64

  int bid = blockIdx.x;             // 128 planes * 8 rowtiles * 4 coltiles
  int n   = bid >> 5;
  int t   = bid & 31;
  int itop0 = (t >> 2) * 16;        // 0..112
  int j0    = (t & 3) * 64;
  int tid = threadIdx.x;
  const float* xp = x + (size_t)n * (H*Wd);

  float w1r[4][9], b1r[4], wredr[4], wsp[9], bsp[9];
  float bredr = bred[0];
#pragma unroll
  for (int m=0;m<4;m++){
    b1r[m] = b1[m]; wredr[m] = Wred[m];
#pragma unroll
    for (int k=0;k<9;k++) w1r[m][k] = W1[m*9+k];
  }
#pragma unroll
  for (int k=0;k<9;k++){ wsp[k] = Wspan[k]; bsp[k] = bspan[k]; }

  for (int idx=tid; idx<20*68; idx+=256){
    int r = idx/68, c = idx%68;
    int row = itop0-2+r, col = j0-2+c;
    xt[r][c] = (row>=0 && row<H && col>=0 && col<Wd) ? xp[row*Wd+col] : 0.f;
  }
  for (int idx=tid; idx<18*68; idx+=256){
    int r = idx/68, c = idx%68;
    int row = 127+itop0+r, col = j0-2+c;
    xb[r][c] = (row<H && col>=0 && col<Wd) ? xp[row*Wd+col] : 0.f;
  }
  __syncthreads();

  // f_top into LDS. Zero outside top's own bounds (patches zero-pad at rows
  // <0 / >127 and cols <0 / >255 of the H2 x W image).
#pragma unroll
  for (int m=0;m<4;m++){
    for (int idx=tid; idx<18*66; idx+=256){
      int r = idx/66, c = idx%66;
      int frow = itop0-1+r, fcol = j0-1+c;
      float val = 0.f;
      if (frow>=0 && frow<H2 && fcol>=0 && fcol<Wd){
        float s = b1r[m];
#pragma unroll
        for (int ky=0;ky<3;ky++)
#pragma unroll
          for (int kx=0;kx<3;kx++)
            s = fmaf(xt[r+ky][c+kx], w1r[m][ky*3+kx], s);
        val = mishf(s);
      }
      ft[m][r][c] = val;
    }
  }
  __syncthreads();

  int lr  = tid >> 4;          // 0..15
  int lc4 = (tid & 15) * 4;    // 0..60
  int trow = itop0 + lr;
  int bq = n >> 4, cq = n & 15;

  // g = relu(Wred . f_bot + bred), f_bot = mish(conv1(x)) at row 128+trow
  float gv[4];
#pragma unroll
  for (int p=0;p<4;p++){
    float g = bredr;
#pragma unroll
    for (int m=0;m<4;m++){
      float s = b1r[m];
#pragma unroll
      for (int ky=0;ky<3;ky++)
#pragma unroll
        for (int kx=0;kx<3;kx++)
          s = fmaf(xb[lr+ky][lc4+p+1+kx], w1r[m][ky*3+kx], s);
      g = fmaf(mishf(s), wredr[m], g);
    }
    gv[p] = fmaxf(g, 0.f);
  }

  size_t planebase = ((size_t)(bq*64 + cq*4)) * (H*Wd) + (size_t)trow*Wd + j0 + lc4;
#pragma unroll
  for (int m=0;m<4;m++){
    float o[4];
#pragma unroll
    for (int p=0;p<4;p++){
      float A = 0.f, Bv = 0.f;
#pragma unroll
      for (int ky=0;ky<3;ky++)
#pragma unroll
        for (int kx=0;kx<3;kx++){
          float tvv = ft[m][lr+ky][lc4+p+kx];
          A  = fmaf(tvv, wsp[ky*3+kx], A);
          Bv = fmaf(tvv, bsp[ky*3+kx], Bv);
        }
      o[p] = fmaf(gv[p], A, Bv);
    }
    ushort4 hv;
    hv.x = f2bf(o[0]); hv.y = f2bf(o[1]); hv.z = f2bf(o[2]); hv.w = f2bf(o[3]);
    *(ushort4*)(shuf + planebase + (size_t)m*(H*Wd)) = hv;
  }
}

// ---------------------------------------------------------------------------
// K3: conv2 (64->16ch 3x3) + bias + mish + spatial-mean partial sums.
// Tile 16x64 per block for one batch b; 16 oc accumulated in regs (4 px/thr).
// Weights read from global with uniform indices -> scalar loads (K$ path).
// ---------------------------------------------------------------------------
__global__ __launch_bounds__(256) void k3_conv2(
    const ushort_t* __restrict__ shuf, const float* __restrict__ W2,
    const float* __restrict__ b2, float* __restrict__ pooled)
{
  __shared__ float sh[4][18][68];
  __shared__ float red[4][16];

  int bid = blockIdx.x;            // 8 b * 16 rowtiles * 4 coltiles = 512
  int b   = bid >> 6;
  int t   = bid & 63;
  int i0  = (t >> 2) * 16;
  int j0  = (t & 3) * 64;
  int tid = threadIdx.x;
  int lr  = tid >> 4, lc4 = (tid & 15)*4;

  float acc[16][4];
#pragma unroll
  for (int oc=0;oc<16;oc++)
#pragma unroll
    for (int p=0;p<4;p++) acc[oc][p] = 0.f;

  const ushort_t* sb = shuf + (size_t)b * 64 * H * Wd;

  for (int chunk=0; chunk<16; ++chunk){
    __syncthreads();
#pragma unroll
    for (int icl=0; icl<4; ++icl){
      const ushort_t* pl = sb + (size_t)(chunk*4+icl) * (H*Wd);
      for (int idx=tid; idx<18*66; idx+=256){
        int r = idx/66, c = idx%66;
        int row = i0-1+r, col = j0-1+c;
        sh[icl][r][c] = (row>=0 && row<H && col>=0 && col<Wd)
                        ? bf2f(pl[row*Wd+col]) : 0.f;
      }
    }
    __syncthreads();
#pragma unroll
    for (int icl=0; icl<4; ++icl){
      float tv[3][6];
#pragma unroll
      for (int ky=0;ky<3;ky++)
#pragma unroll
        for (int c=0;c<6;c++)
          tv[ky][c] = sh[icl][lr+ky][lc4+c];
      const float* wp = W2 + (size_t)(chunk*4+icl)*9;
#pragma unroll
      for (int ky=0;ky<3;ky++)
#pragma unroll
        for (int kx=0;kx<3;kx++){
#pragma unroll
          for (int oc=0; oc<16; ++oc){
            float wv = wp[oc*576 + ky*3 + kx];
#pragma unroll
            for (int p=0;p<4;p++)
              acc[oc][p] = fmaf(tv[ky][kx+p], wv, acc[oc][p]);
          }
        }
    }
  }

  // bias + mish + per-thread sum, then block reduce -> atomicAdd
  float ps[16];
#pragma unroll
  for (int oc=0;oc<16;oc++){
    float bv = b2[oc];
    float s = 0.f;
#pragma unroll
    for (int p=0;p<4;p++) s += mishf(acc[oc][p] + bv);
#pragma unroll
    for (int off=32; off; off>>=1) s += __shfl_xor(s, off);
    ps[oc] = s;
  }
  int wid = tid >> 6, lane = tid & 63;
  if (lane == 0){
#pragma unroll
    for (int oc=0;oc<16;oc++) red[wid][oc] = ps[oc];
  }
  __syncthreads();
  if (tid < 16){
    float tot = red[0][tid] + red[1][tid] + red[2][tid] + red[3][tid];
    atomicAdd(&pooled[b*16+tid], tot);
  }
}

// ---------------------------------------------------------------------------
// K4: ECA gate from pooled sums. 1 block, 128 threads.
// ---------------------------------------------------------------------------
__global__ void k4_gate(const float* __restrict__ pooled,
                        const float* __restrict__ Weca,
                        float* __restrict__ gate)
{
  int t = threadIdx.x;           // 0..127
  if (t >= 128) return;
  int b = t >> 4, c = t & 15;
  const float s = 1.0f / 65536.0f;
  float pm = (c > 0)  ? pooled[b*16+c-1]*s : 0.f;
  float p0 =            pooled[b*16+c  ]*s;
  float pp = (c < 15) ? pooled[b*16+c+1]*s : 0.f;
  float z = Weca[0]*pm + Weca[1]*p0 + Weca[2]*pp;
  gate[t] = 1.f / (1.f + __expf(-z));
}

// ---------------------------------------------------------------------------
// K5: out = x * gate[b,c]
// ---------------------------------------------------------------------------
__global__ __launch_bounds__(256) void k5_scale(
    const float4* __restrict__ x4, const float* __restrict__ gate,
    float4* __restrict__ out4)
{
  int idx = blockIdx.x*256 + threadIdx.x;   // < 2097152
  float g = gate[idx >> 14];                // 16384 float4 per (b,c) plane
  float4 v = x4[idx];
  v.x *= g; v.y *= g; v.z *= g; v.w *= g;
  out4[idx] = v;
}

extern "C" void kernel_launch(void* const* d_in, const int* in_sizes, int n_in,
                              void* d_out, int out_size, void* d_ws, size_t ws_size,
                              hipStream_t stream)
{
  const float* x     = (const float*)d_in[0];
  const float* W1    = (const float*)d_in[1];
  const float* b1    = (const float*)d_in[2];
  const float* Wred  = (const float*)d_in[3];
  const float* bred  = (const float*)d_in[4];
  const float* Wspan = (const float*)d_in[5];
  const float* bspan = (const float*)d_in[6];
  const float* W2    = (const float*)d_in[7];
  const float* b2    = (const float*)d_in[8];
  const float* Weca  = (const float*)d_in[9];

  ushort_t* shuf  = (ushort_t*)d_ws;                          // 64 MiB bf16
  float*    pooled = (float*)((char*)d_ws + 67108864);        // 512 B
  float*    gate   = (float*)((char*)d_ws + 67108864 + 512);  // 512 B

  hipMemsetAsync(pooled, 0, 512, stream);

  k1_bot <<<4096, 256, 0, stream>>>(x, W1, b1, shuf);
  k2_top <<<4096, 256, 0, stream>>>(x, W1, b1, Wred, bred, Wspan, bspan, shuf);
  k3_conv2<<<512, 256, 0, stream>>>(shuf, W2, b2, pooled);
  k4_gate<<<1, 128, 0, stream>>>(pooled, Weca, gate);
  k5_scale<<<8192, 256, 0, stream>>>((const float4*)x, gate, (float4*)d_out);
}

// Round 2
// 142.817 us; speedup vs baseline: 2.3080x; 2.3080x over previous
//
#include <hip/hip_runtime.h>
#include <hip/hip_bf16.h>

#define H 256
#define Wd 256
#define H2 128

typedef unsigned short ushort_t;
typedef __attribute__((ext_vector_type(8))) short short8;
typedef __attribute__((ext_vector_type(4))) float f32x4;

__device__ __forceinline__ float mishf(float v){
  if (v > 15.f) return v;
  float e = __expf(v);
  float w = e*(e+2.f);
  return v * (w / (w + 2.f));
}

__device__ __forceinline__ ushort_t f2bf(float f){
  unsigned int u = __float_as_uint(f);
  u += 0x7fffu + ((u >> 16) & 1u);
  return (ushort_t)(u >> 16);
}

// ---------------------------------------------------------------------------
// shuf layout: 8-byte pixel records  [plane = b*16 + c][i*256 + j][m0..3]
// (bf16 x4 per record). k1 writes bottom rows (rolled c), k2 top rows.
// ---------------------------------------------------------------------------

// K1: bottom half. f_bot = mish(conv1(x)) rows [128,256) -> plane (b,(c-1)%16)
__global__ __launch_bounds__(256) void k1_bot(
    const float* __restrict__ x, const float* __restrict__ W1,
    const float* __restrict__ b1, ushort_t* __restrict__ shuf)
{
  int bid = blockIdx.x;          // 128 planes * 32 rowgroups
  int n   = bid >> 5;
  int rg  = bid & 31;
  int tid = threadIdx.x;
  int i   = 128 + rg*4 + (tid >> 6);
  int j0  = (tid & 63) * 4;
  const float* xp = x + (size_t)n * (H*Wd);

  float w[4][9], bb[4];
#pragma unroll
  for (int m=0;m<4;m++){
    bb[m] = b1[m];
#pragma unroll
    for (int k=0;k<9;k++) w[m][k] = W1[m*9+k];
  }

  float xv[3][6];
#pragma unroll
  for (int r=0;r<3;r++){
    int row = i-1+r;               // >=127 always
    bool rok = (row < H);
#pragma unroll
    for (int c=0;c<6;c++){
      int col = j0-1+c;
      xv[r][c] = (rok && col>=0 && col<Wd) ? xp[row*Wd+col] : 0.f;
    }
  }

  int b = n >> 4, cs = n & 15;
  int cdst = (cs + 15) & 15;
  float o[4][4];
#pragma unroll
  for (int m=0;m<4;m++){
#pragma unroll
    for (int p=0;p<4;p++){
      float s = bb[m];
#pragma unroll
      for (int ky=0;ky<3;ky++)
#pragma unroll
        for (int kx=0;kx<3;kx++)
          s = fmaf(xv[ky][p+kx], w[m][ky*3+kx], s);
      o[m][p] = mishf(s);
    }
  }
  size_t pbase = ((size_t)(b*16 + cdst))*65536 + (size_t)i*256 + j0;
#pragma unroll
  for (int p=0;p<4;p++){
    ushort4 hv;
    hv.x = f2bf(o[0][p]); hv.y = f2bf(o[1][p]);
    hv.z = f2bf(o[2][p]); hv.w = f2bf(o[3][p]);
    *(ushort4*)(shuf + (pbase + p)*4) = hv;
  }
}

// K2: top half. ti = g*(Wspan (*) f_top) + (bspan (*) f_top) -> plane (b,c)
__global__ __launch_bounds__(256) void k2_top(
    const float* __restrict__ x, const float* __restrict__ W1,
    const float* __restrict__ b1, const float* __restrict__ Wred,
    const float* __restrict__ bred, const float* __restrict__ Wspan,
    const float* __restrict__ bspan, ushort_t* __restrict__ shuf)
{
  __shared__ float xt[20][68];
  __shared__ float xb[18][68];
  __shared__ float ft[4][18][68];

  int bid = blockIdx.x;             // 128 planes * 8 rowtiles * 4 coltiles
  int n   = bid >> 5;
  int t   = bid & 31;
  int itop0 = (t >> 2) * 16;
  int j0    = (t & 3) * 64;
  int tid = threadIdx.x;
  const float* xp = x + (size_t)n * (H*Wd);

  float w1r[4][9], b1r[4], wredr[4], wsp[9], bsp[9];
  float bredr = bred[0];
#pragma unroll
  for (int m=0;m<4;m++){
    b1r[m] = b1[m]; wredr[m] = Wred[m];
#pragma unroll
    for (int k=0;k<9;k++) w1r[m][k] = W1[m*9+k];
  }
#pragma unroll
  for (int k=0;k<9;k++){ wsp[k] = Wspan[k]; bsp[k] = bspan[k]; }

  for (int idx=tid; idx<20*68; idx+=256){
    int r = idx/68, c = idx%68;
    int row = itop0-2+r, col = j0-2+c;
    xt[r][c] = (row>=0 && row<H && col>=0 && col<Wd) ? xp[row*Wd+col] : 0.f;
  }
  for (int idx=tid; idx<18*68; idx+=256){
    int r = idx/68, c = idx%68;
    int row = 127+itop0+r, col = j0-2+c;
    xb[r][c] = (row<H && col>=0 && col<Wd) ? xp[row*Wd+col] : 0.f;
  }
  __syncthreads();

#pragma unroll
  for (int m=0;m<4;m++){
    for (int idx=tid; idx<18*66; idx+=256){
      int r = idx/66, c = idx%66;
      int frow = itop0-1+r, fcol = j0-1+c;
      float val = 0.f;
      if (frow>=0 && frow<H2 && fcol>=0 && fcol<Wd){
        float s = b1r[m];
#pragma unroll
        for (int ky=0;ky<3;ky++)
#pragma unroll
          for (int kx=0;kx<3;kx++)
            s = fmaf(xt[r+ky][c+kx], w1r[m][ky*3+kx], s);
        val = mishf(s);
      }
      ft[m][r][c] = val;
    }
  }
  __syncthreads();

  int lr  = tid >> 4;
  int lc4 = (tid & 15) * 4;
  int trow = itop0 + lr;
  int bq = n >> 4, cq = n & 15;

  float gv[4];
#pragma unroll
  for (int p=0;p<4;p++){
    float g = bredr;
#pragma unroll
    for (int m=0;m<4;m++){
      float s = b1r[m];
#pragma unroll
      for (int ky=0;ky<3;ky++)
#pragma unroll
        for (int kx=0;kx<3;kx++)
          s = fmaf(xb[lr+ky][lc4+p+1+kx], w1r[m][ky*3+kx], s);
      g = fmaf(mishf(s), wredr[m], g);
    }
    gv[p] = fmaxf(g, 0.f);
  }

  float o[4][4];
#pragma unroll
  for (int m=0;m<4;m++){
#pragma unroll
    for (int p=0;p<4;p++){
      float A = 0.f, Bv = 0.f;
#pragma unroll
      for (int ky=0;ky<3;ky++)
#pragma unroll
        for (int kx=0;kx<3;kx++){
          float tvv = ft[m][lr+ky][lc4+p+kx];
          A  = fmaf(tvv, wsp[ky*3+kx], A);
          Bv = fmaf(tvv, bsp[ky*3+kx], Bv);
        }
      o[m][p] = fmaf(gv[p], A, Bv);
    }
  }
  size_t pbase = ((size_t)(bq*16 + cq))*65536 + (size_t)trow*256 + j0 + lc4;
#pragma unroll
  for (int p=0;p<4;p++){
    ushort4 hv;
    hv.x = f2bf(o[0][p]); hv.y = f2bf(o[1][p]);
    hv.z = f2bf(o[2][p]); hv.w = f2bf(o[3][p]);
    *(ushort4*)(shuf + (pbase + p)*4) = hv;
  }
}

// ---------------------------------------------------------------------------
// K3: conv2 via MFMA implicit GEMM. M=16 oc, N=16 px, K=576 (9 shifts x 64ch).
// Block: 8x32 px tile of one batch, halo 10x34 staged in LDS (stride 144B).
// 4 waves = (colhalf, khalf); khalf partials merged in LDS; mish+pool ->
// per-block partials in scratch.
// ---------------------------------------------------------------------------
__global__ __launch_bounds__(256) void k3_conv2(
    const ushort_t* __restrict__ shuf, const float* __restrict__ W2,
    const float* __restrict__ b2, float* __restrict__ scratch)
{
  __shared__ __align__(16) char smem[340*144];
  __shared__ float pacc[16];

  int bid = blockIdx.x;            // 8 b * 32 rowblocks * 8 colblocks = 2048
  int b   = bid >> 8;
  int t   = bid & 255;
  int rb  = t >> 3;
  int cb  = t & 7;
  int tid = threadIdx.x;
  int lane = tid & 63;
  int n = tid & 15;
  int g = (tid >> 4) & 3;
  int wid = tid >> 6;
  int colhalf = wid & 1;
  int khalf   = wid >> 1;

  if (tid < 16) pacc[tid] = 0.f;

  // A fragments: afr[s][e] = W2[oc][ch][s], oc=lane&15, ch=khalf*32+g*8+e
  short8 afr[9];
#pragma unroll
  for (int s = 0; s < 9; ++s){
#pragma unroll
    for (int e = 0; e < 8; ++e){
      int ch = khalf*32 + g*8 + e;
      afr[s][e] = (short)f2bf(W2[(n*64 + ch)*9 + s]);
    }
  }

  // stage 10x34 halo px, 8 slots of 16B each (slot gp = planes 2gp,2gp+1)
  int r0 = rb*8 - 1, c0 = cb*32 - 1;
  const ushort_t* sp = shuf + (size_t)(b*16)*262144;
  for (int idx = tid; idx < 2720; idx += 256){
    int gp = idx / 340;
    int px = idx - gp*340;
    int hr = px / 34;
    int hc = px - hr*34;
    int grow = r0 + hr, gcol = c0 + hc;
    uint2 va = make_uint2(0u,0u), vb = make_uint2(0u,0u);
    if ((unsigned)grow < 256u && (unsigned)gcol < 256u){
      const ushort_t* pp = sp + (size_t)(2*gp)*262144 + (size_t)(grow*256 + gcol)*4;
      va = *(const uint2*)pp;
      vb = *(const uint2*)(pp + 262144);
    }
    uint4 wv; wv.x = va.x; wv.y = va.y; wv.z = vb.x; wv.w = vb.y;
    *(uint4*)(smem + px*144 + gp*16) = wv;
  }
  __syncthreads();

  f32x4 acc[8];
#pragma unroll
  for (int r = 0; r < 8; ++r) acc[r] = f32x4{0.f,0.f,0.f,0.f};

  int cbase = colhalf*16 + n;
  int sbase = (khalf*4 + g)*16;
#pragma unroll
  for (int hr = 0; hr < 10; ++hr){
#pragma unroll
    for (int kx = 0; kx < 3; ++kx){
      int pxl = hr*34 + cbase + kx;
      short8 bf = *(const short8*)(smem + pxl*144 + sbase);
#pragma unroll
      for (int ky = 0; ky < 3; ++ky){
        int orow = hr - ky;
        if (orow >= 0 && orow < 8){
          acc[orow] = __builtin_amdgcn_mfma_f32_16x16x32_bf16(
              afr[ky*3+kx], bf, acc[orow], 0, 0, 0);
        }
      }
    }
  }
  __syncthreads();

  // merge khalf partials via LDS (reuse staging region)
  f32x4* mg = (f32x4*)smem;
  if (khalf == 1){
#pragma unroll
    for (int r = 0; r < 8; ++r) mg[(colhalf*8 + r)*64 + lane] = acc[r];
  }
  __syncthreads();

  if (khalf == 0){
    float b2v[4];
#pragma unroll
    for (int q = 0; q < 4; ++q) b2v[q] = b2[g*4 + q];
    float po[4] = {0.f, 0.f, 0.f, 0.f};
#pragma unroll
    for (int r = 0; r < 8; ++r){
      f32x4 o = acc[r] + mg[(colhalf*8 + r)*64 + lane];
#pragma unroll
      for (int q = 0; q < 4; ++q) po[q] += mishf(o[q] + b2v[q]);
    }
#pragma unroll
    for (int q = 0; q < 4; ++q){
#pragma unroll
      for (int mk = 1; mk < 16; mk <<= 1) po[q] += __shfl_xor(po[q], mk);
    }
    if (n == 0){
#pragma unroll
      for (int q = 0; q < 4; ++q) atomicAdd(&pacc[g*4 + q], po[q]);
    }
  }
  __syncthreads();
  if (tid < 16) scratch[bid*16 + tid] = pacc[tid];
}

// K4: reduce per-block partials -> pooled mean -> ECA gate. One block per b.
__global__ void k4_gate(const float* __restrict__ scratch,
                        const float* __restrict__ Weca,
                        float* __restrict__ gate)
{
  __shared__ float rr[16][16];
  __shared__ float pool[16];
  int b = blockIdx.x;
  int t = threadIdx.x;           // 256
  int oc = t & 15, ch = t >> 4;
  float s = 0.f;
  for (int u = 0; u < 16; ++u)
    s += scratch[(size_t)(b*256 + ch*16 + u)*16 + oc];
  rr[ch][oc] = s;
  __syncthreads();
  if (t < 16){
    float tot = 0.f;
#pragma unroll
    for (int k = 0; k < 16; ++k) tot += rr[k][t];
    pool[t] = tot * (1.0f/65536.0f);
  }
  __syncthreads();
  if (t < 16){
    float pm = (t > 0)  ? pool[t-1] : 0.f;
    float p0 = pool[t];
    float pp = (t < 15) ? pool[t+1] : 0.f;
    float z = Weca[0]*pm + Weca[1]*p0 + Weca[2]*pp;
    gate[b*16 + t] = 1.f/(1.f + __expf(-z));
  }
}

// K5: out = x * gate[b,c]
__global__ __launch_bounds__(256) void k5_scale(
    const float4* __restrict__ x4, const float* __restrict__ gate,
    float4* __restrict__ out4)
{
  int idx = blockIdx.x*256 + threadIdx.x;
  float g = gate[idx >> 14];
  float4 v = x4[idx];
  v.x *= g; v.y *= g; v.z *= g; v.w *= g;
  out4[idx] = v;
}

extern "C" void kernel_launch(void* const* d_in, const int* in_sizes, int n_in,
                              void* d_out, int out_size, void* d_ws, size_t ws_size,
                              hipStream_t stream)
{
  const float* x     = (const float*)d_in[0];
  const float* W1    = (const float*)d_in[1];
  const float* b1    = (const float*)d_in[2];
  const float* Wred  = (const float*)d_in[3];
  const float* bred  = (const float*)d_in[4];
  const float* Wspan = (const float*)d_in[5];
  const float* bspan = (const float*)d_in[6];
  const float* W2    = (const float*)d_in[7];
  const float* b2    = (const float*)d_in[8];
  const float* Weca  = (const float*)d_in[9];

  ushort_t* shuf    = (ushort_t*)d_ws;                    // 64 MiB bf16 records
  float*    gate    = (float*)((char*)d_ws + 67108864);   // 512 B
  float*    scratch = (float*)d_out;  // 2048*16 floats; overwritten by k5 later

  k1_bot <<<4096, 256, 0, stream>>>(x, W1, b1, shuf);
  k2_top <<<4096, 256, 0, stream>>>(x, W1, b1, Wred, bred, Wspan, bspan, shuf);
  k3_conv2<<<2048, 256, 0, stream>>>(shuf, W2, b2, scratch);
  k4_gate<<<8, 256, 0, stream>>>(scratch, Weca, gate);
  k5_scale<<<8192, 256, 0, stream>>>((const float4*)x, gate, (float4*)d_out);
}

// Round 3
// 118.966 us; speedup vs baseline: 2.7707x; 1.2005x over previous
//
#include <hip/hip_runtime.h>
#include <hip/hip_bf16.h>

#define H 256
#define Wd 256
#define H2 128

typedef unsigned short ushort_t;
typedef __attribute__((ext_vector_type(8))) short short8;
typedef __attribute__((ext_vector_type(4))) float f32x4;

__device__ __forceinline__ float mishf(float v){
  if (v > 15.f) return v;
  float e = __expf(v);
  float w = e*(e+2.f);
  return v * (w / (w + 2.f));
}

__device__ __forceinline__ ushort_t f2bf(float f){
  unsigned int u = __float_as_uint(f);
  u += 0x7fffu + ((u >> 16) & 1u);
  return (ushort_t)(u >> 16);
}
__device__ __forceinline__ float bf2f(ushort_t h){
  return __uint_as_float(((unsigned int)h) << 16);
}

// ---------------------------------------------------------------------------
// shuf layout: 8-byte pixel records  [plane = b*16 + c][i*256 + j][m0..3]
// (bf16 x4). k1 writes bottom rows (rolled c), k2 top rows.
// ---------------------------------------------------------------------------

// K1: bottom half. f_bot = mish(conv1(x)) rows [128,256) -> plane (b,(c-1)%16)
__global__ __launch_bounds__(256) void k1_bot(
    const float* __restrict__ x, const float* __restrict__ W1,
    const float* __restrict__ b1, ushort_t* __restrict__ shuf)
{
  int bid = blockIdx.x;          // 128 planes * 32 rowgroups
  int n   = bid >> 5;
  int rg  = bid & 31;
  int tid = threadIdx.x;
  int i   = 128 + rg*4 + (tid >> 6);
  int j0  = (tid & 63) * 4;
  const float* xp = x + (size_t)n * (H*Wd);

  float w[4][9], bb[4];
#pragma unroll
  for (int m=0;m<4;m++){
    bb[m] = b1[m];
#pragma unroll
    for (int k=0;k<9;k++) w[m][k] = W1[m*9+k];
  }

  float xv[3][6];
#pragma unroll
  for (int r=0;r<3;r++){
    int row = i-1+r;               // >=127 always
    bool rok = (row < H);
#pragma unroll
    for (int c=0;c<6;c++){
      int col = j0-1+c;
      xv[r][c] = (rok && col>=0 && col<Wd) ? xp[row*Wd+col] : 0.f;
    }
  }

  int b = n >> 4, cs = n & 15;
  int cdst = (cs + 15) & 15;
  float o[4][4];
#pragma unroll
  for (int m=0;m<4;m++){
#pragma unroll
    for (int p=0;p<4;p++){
      float s = bb[m];
#pragma unroll
      for (int ky=0;ky<3;ky++)
#pragma unroll
        for (int kx=0;kx<3;kx++)
          s = fmaf(xv[ky][p+kx], w[m][ky*3+kx], s);
      o[m][p] = mishf(s);
    }
  }
  size_t pbase = ((size_t)(b*16 + cdst))*65536 + (size_t)i*256 + j0;
#pragma unroll
  for (int p=0;p<4;p++){
    ushort4 hv;
    hv.x = f2bf(o[0][p]); hv.y = f2bf(o[1][p]);
    hv.z = f2bf(o[2][p]); hv.w = f2bf(o[3][p]);
    *(ushort4*)(shuf + (pbase + p)*4) = hv;
  }
}

// ---------------------------------------------------------------------------
// K2: top half. f_top tile in LDS (from x), g read back from shuf (f_bot was
// written by k1 -- stream order guarantees availability), then
// ti = g*(Wspan (*) f_top) + (bspan (*) f_top) -> plane (b,c) top rows.
// LDS strides padded to 69 floats (odd) -> conflict-free span reads.
// ---------------------------------------------------------------------------
__global__ __launch_bounds__(256) void k2_top(
    const float* __restrict__ x, const float* __restrict__ W1,
    const float* __restrict__ b1, const float* __restrict__ Wred,
    const float* __restrict__ bred, const float* __restrict__ Wspan,
    const float* __restrict__ bspan, ushort_t* __restrict__ shuf)
{
  __shared__ float xt[20][69];
  __shared__ float ft[4][18][69];

  int bid = blockIdx.x;             // 128 planes * 8 rowtiles * 4 coltiles
  int n   = bid >> 5;
  int t   = bid & 31;
  int itop0 = (t >> 2) * 16;
  int j0    = (t & 3) * 64;
  int tid = threadIdx.x;
  const float* xp = x + (size_t)n * (H*Wd);

  float w1r[4][9], b1r[4], wredr[4], wsp[9], bsp[9];
  float bredr = bred[0];
#pragma unroll
  for (int m=0;m<4;m++){
    b1r[m] = b1[m]; wredr[m] = Wred[m];
#pragma unroll
    for (int k=0;k<9;k++) w1r[m][k] = W1[m*9+k];
  }
#pragma unroll
  for (int k=0;k<9;k++){ wsp[k] = Wspan[k]; bsp[k] = bspan[k]; }

  // stage x rows [itop0-2, itop0+17], cols [j0-2, j0+65]
  for (int idx=tid; idx<20*68; idx+=256){
    int r = idx/68, c = idx - r*68;
    int row = itop0-2+r, col = j0-2+c;
    xt[r][c] = (row>=0 && col>=0 && col<Wd) ? xp[row*Wd+col] : 0.f;
  }
  __syncthreads();

  // f_top rows [itop0-1, itop0+16], cols [j0-1, j0+64]; all 4 m per element.
  for (int idx=tid; idx<18*66; idx+=256){
    int r = idx/66, c = idx - r*66;
    int frow = itop0-1+r, fcol = j0-1+c;
    bool ok = (frow>=0 && frow<H2 && fcol<Wd && fcol>=0);
    float xv[3][3];
#pragma unroll
    for (int ky=0;ky<3;ky++)
#pragma unroll
      for (int kx=0;kx<3;kx++) xv[ky][kx] = xt[r+ky][c+kx];
#pragma unroll
    for (int m=0;m<4;m++){
      float s = b1r[m];
#pragma unroll
      for (int ky=0;ky<3;ky++)
#pragma unroll
        for (int kx=0;kx<3;kx++)
          s = fmaf(xv[ky][kx], w1r[m][ky*3+kx], s);
      ft[m][r][c] = ok ? mishf(s) : 0.f;
    }
  }
  __syncthreads();

  int lr  = tid >> 4;
  int lc4 = (tid & 15) * 4;
  int trow = itop0 + lr;
  int bq = n >> 4, cq = n & 15;

  // g = relu(Wred . f_bot + bred); f_bot read from shuf (written by k1 at
  // rolled plane (c+15)&15, bottom rows).
  int nb = bq*16 + ((cq + 15) & 15);
  const ushort4* fbp = (const ushort4*)(shuf +
      ((size_t)nb*65536 + (size_t)(128+trow)*256 + (j0+lc4))*4);
  float gv[4];
#pragma unroll
  for (int p=0;p<4;p++){
    ushort4 rec = fbp[p];
    float s = bredr;
    s = fmaf(bf2f(rec.x), wredr[0], s);
    s = fmaf(bf2f(rec.y), wredr[1], s);
    s = fmaf(bf2f(rec.z), wredr[2], s);
    s = fmaf(bf2f(rec.w), wredr[3], s);
    gv[p] = fmaxf(s, 0.f);
  }

  float o[4][4];
#pragma unroll
  for (int m=0;m<4;m++){
    float fv[3][6];
#pragma unroll
    for (int ky=0;ky<3;ky++)
#pragma unroll
      for (int c=0;c<6;c++)
        fv[ky][c] = ft[m][lr+ky][lc4+c];
#pragma unroll
    for (int p=0;p<4;p++){
      float A = 0.f, Bv = 0.f;
#pragma unroll
      for (int ky=0;ky<3;ky++)
#pragma unroll
        for (int kx=0;kx<3;kx++){
          A  = fmaf(fv[ky][p+kx], wsp[ky*3+kx], A);
          Bv = fmaf(fv[ky][p+kx], bsp[ky*3+kx], Bv);
        }
      o[m][p] = fmaf(gv[p], A, Bv);
    }
  }
  size_t pbase = ((size_t)(bq*16 + cq))*65536 + (size_t)trow*256 + j0 + lc4;
#pragma unroll
  for (int p=0;p<4;p++){
    ushort4 hv;
    hv.x = f2bf(o[0][p]); hv.y = f2bf(o[1][p]);
    hv.z = f2bf(o[2][p]); hv.w = f2bf(o[3][p]);
    *(ushort4*)(shuf + (pbase + p)*4) = hv;
  }
}

// ---------------------------------------------------------------------------
// K3: conv2 via MFMA implicit GEMM. M=16 oc, N=16 px, K=576 (9 shifts x 64ch).
// Block: 8x32 px tile of one batch, halo 10x34 staged in LDS (stride 144B).
// 4 waves = (colhalf, khalf); khalf partials merged in LDS; mish+pool ->
// per-block partials in scratch.
// ---------------------------------------------------------------------------
__global__ __launch_bounds__(256) void k3_conv2(
    const ushort_t* __restrict__ shuf, const float* __restrict__ W2,
    const float* __restrict__ b2, float* __restrict__ scratch)
{
  __shared__ __align__(16) char smem[340*144];
  __shared__ float pacc[16];

  int bid = blockIdx.x;            // 8 b * 32 rowblocks * 8 colblocks = 2048
  int b   = bid >> 8;
  int t   = bid & 255;
  int rb  = t >> 3;
  int cb  = t & 7;
  int tid = threadIdx.x;
  int lane = tid & 63;
  int n = tid & 15;
  int g = (tid >> 4) & 3;
  int wid = tid >> 6;
  int colhalf = wid & 1;
  int khalf   = wid >> 1;

  if (tid < 16) pacc[tid] = 0.f;

  // A fragments: afr[s][e] = W2[oc][ch][s], oc=lane&15, ch=khalf*32+g*8+e
  short8 afr[9];
#pragma unroll
  for (int s = 0; s < 9; ++s){
#pragma unroll
    for (int e = 0; e < 8; ++e){
      int ch = khalf*32 + g*8 + e;
      afr[s][e] = (short)f2bf(W2[(n*64 + ch)*9 + s]);
    }
  }

  // stage 10x34 halo px, 8 slots of 16B each (slot gp = planes 2gp,2gp+1)
  int r0 = rb*8 - 1, c0 = cb*32 - 1;
  const ushort_t* sp = shuf + (size_t)(b*16)*262144;
  for (int idx = tid; idx < 2720; idx += 256){
    int gp = idx / 340;
    int px = idx - gp*340;
    int hr = px / 34;
    int hc = px - hr*34;
    int grow = r0 + hr, gcol = c0 + hc;
    uint2 va = make_uint2(0u,0u), vb = make_uint2(0u,0u);
    if ((unsigned)grow < 256u && (unsigned)gcol < 256u){
      const ushort_t* pp = sp + (size_t)(2*gp)*262144 + (size_t)(grow*256 + gcol)*4;
      va = *(const uint2*)pp;
      vb = *(const uint2*)(pp + 262144);
    }
    uint4 wv; wv.x = va.x; wv.y = va.y; wv.z = vb.x; wv.w = vb.y;
    *(uint4*)(smem + px*144 + gp*16) = wv;
  }
  __syncthreads();

  f32x4 acc[8];
#pragma unroll
  for (int r = 0; r < 8; ++r) acc[r] = f32x4{0.f,0.f,0.f,0.f};

  int cbase = colhalf*16 + n;
  int sbase = (khalf*4 + g)*16;
#pragma unroll
  for (int hr = 0; hr < 10; ++hr){
#pragma unroll
    for (int kx = 0; kx < 3; ++kx){
      int pxl = hr*34 + cbase + kx;
      short8 bf = *(const short8*)(smem + pxl*144 + sbase);
#pragma unroll
      for (int ky = 0; ky < 3; ++ky){
        int orow = hr - ky;
        if (orow >= 0 && orow < 8){
          acc[orow] = __builtin_amdgcn_mfma_f32_16x16x32_bf16(
              afr[ky*3+kx], bf, acc[orow], 0, 0, 0);
        }
      }
    }
  }
  __syncthreads();

  // merge khalf partials via LDS (reuse staging region)
  f32x4* mg = (f32x4*)smem;
  if (khalf == 1){
#pragma unroll
    for (int r = 0; r < 8; ++r) mg[(colhalf*8 + r)*64 + lane] = acc[r];
  }
  __syncthreads();

  if (khalf == 0){
    float b2v[4];
#pragma unroll
    for (int q = 0; q < 4; ++q) b2v[q] = b2[g*4 + q];
    float po[4] = {0.f, 0.f, 0.f, 0.f};
#pragma unroll
    for (int r = 0; r < 8; ++r){
      f32x4 o = acc[r] + mg[(colhalf*8 + r)*64 + lane];
#pragma unroll
      for (int q = 0; q < 4; ++q) po[q] += mishf(o[q] + b2v[q]);
    }
#pragma unroll
    for (int q = 0; q < 4; ++q){
#pragma unroll
      for (int mk = 1; mk < 16; mk <<= 1) po[q] += __shfl_xor(po[q], mk);
    }
    if (n == 0){
#pragma unroll
      for (int q = 0; q < 4; ++q) atomicAdd(&pacc[g*4 + q], po[q]);
    }
  }
  __syncthreads();
  if (tid < 16) scratch[bid*16 + tid] = pacc[tid];
}

// K4: reduce per-block partials -> pooled mean -> ECA gate. One block per b.
__global__ void k4_gate(const float* __restrict__ scratch,
                        const float* __restrict__ Weca,
                        float* __restrict__ gate)
{
  __shared__ float rr[16][16];
  __shared__ float pool[16];
  int b = blockIdx.x;
  int t = threadIdx.x;           // 256
  int oc = t & 15, ch = t >> 4;
  float s = 0.f;
  for (int u = 0; u < 16; ++u)
    s += scratch[(size_t)(b*256 + ch*16 + u)*16 + oc];
  rr[ch][oc] = s;
  __syncthreads();
  if (t < 16){
    float tot = 0.f;
#pragma unroll
    for (int k = 0; k < 16; ++k) tot += rr[k][t];
    pool[t] = tot * (1.0f/65536.0f);
  }
  __syncthreads();
  if (t < 16){
    float pm = (t > 0)  ? pool[t-1] : 0.f;
    float p0 = pool[t];
    float pp = (t < 15) ? pool[t+1] : 0.f;
    float z = Weca[0]*pm + Weca[1]*p0 + Weca[2]*pp;
    gate[b*16 + t] = 1.f/(1.f + __expf(-z));
  }
}

// K5: out = x * gate[b,c]
__global__ __launch_bounds__(256) void k5_scale(
    const float4* __restrict__ x4, const float* __restrict__ gate,
    float4* __restrict__ out4)
{
  int idx = blockIdx.x*256 + threadIdx.x;
  float g = gate[idx >> 14];
  float4 v = x4[idx];
  v.x *= g; v.y *= g; v.z *= g; v.w *= g;
  out4[idx] = v;
}

extern "C" void kernel_launch(void* const* d_in, const int* in_sizes, int n_in,
                              void* d_out, int out_size, void* d_ws, size_t ws_size,
                              hipStream_t stream)
{
  const float* x     = (const float*)d_in[0];
  const float* W1    = (const float*)d_in[1];
  const float* b1    = (const float*)d_in[2];
  const float* Wred  = (const float*)d_in[3];
  const float* bred  = (const float*)d_in[4];
  const float* Wspan = (const float*)d_in[5];
  const float* bspan = (const float*)d_in[6];
  const float* W2    = (const float*)d_in[7];
  const float* b2    = (const float*)d_in[8];
  const float* Weca  = (const float*)d_in[9];

  ushort_t* shuf    = (ushort_t*)d_ws;                    // 64 MiB bf16 records
  float*    gate    = (float*)((char*)d_ws + 67108864);   // 512 B
  float*    scratch = (float*)d_out;  // 2048*16 floats; overwritten by k5 later

  k1_bot <<<4096, 256, 0, stream>>>(x, W1, b1, shuf);
  k2_top <<<4096, 256, 0, stream>>>(x, W1, b1, Wred, bred, Wspan, bspan, shuf);
  k3_conv2<<<2048, 256, 0, stream>>>(shuf, W2, b2, scratch);
  k4_gate<<<8, 256, 0, stream>>>(scratch, Weca, gate);
  k5_scale<<<8192, 256, 0, stream>>>((const float4*)x, gate, (float4*)d_out);
}

// Round 4
// 99.246 us; speedup vs baseline: 3.3213x; 1.1987x over previous
//
#include <hip/hip_runtime.h>
#include <hip/hip_bf16.h>

#define H 256
#define Wd 256
#define H2 128

typedef unsigned short ushort_t;
typedef __attribute__((ext_vector_type(8))) short short8;
typedef __attribute__((ext_vector_type(4))) float f32x4;

__device__ __forceinline__ float mishf(float v){
  if (v > 15.f) return v;
  float e = __expf(v);
  float w = e*(e+2.f);
  return v * w * __builtin_amdgcn_rcpf(w + 2.f);
}

__device__ __forceinline__ ushort_t f2bf(float f){
  unsigned int u = __float_as_uint(f);
  u += 0x7fffu + ((u >> 16) & 1u);
  return (ushort_t)(u >> 16);
}
__device__ __forceinline__ float bf2f(ushort_t h){
  return __uint_as_float(((unsigned int)h) << 16);
}

// ---------------------------------------------------------------------------
// shuf layout: 8-byte pixel records  [plane = b*16 + c][i*256 + j][m0..3]
// (bf16 x4). k1 writes bottom rows (rolled c), k2 top rows.
// ---------------------------------------------------------------------------

// K0: pre-pack W2 into bf16 MFMA A-fragment order.
// wpack[khalf][s][lane] = short8{ W2[(n*64 + khalf*32+g*8+e)*9 + s] }, e=0..7
// with n=lane&15, g=lane>>4.  1152 fragments of 16B = 18 KiB.
__global__ void k0_pack(const float* __restrict__ W2, ushort_t* __restrict__ wpack)
{
  int idx = blockIdx.x*128 + threadIdx.x;   // 0..1151
  if (idx >= 1152) return;
  int lane  = idx & 63;
  int s     = (idx >> 6) % 9;
  int khalf = idx / 576;
  int n = lane & 15, g = lane >> 4;
  unsigned int w[4];
#pragma unroll
  for (int h = 0; h < 4; ++h){
    int ch0 = khalf*32 + g*8 + 2*h;
    unsigned lo = f2bf(W2[(n*64 + ch0  )*9 + s]);
    unsigned hi = f2bf(W2[(n*64 + ch0+1)*9 + s]);
    w[h] = lo | (hi << 16);
  }
  *(uint4*)(wpack + (size_t)idx*8) = make_uint4(w[0], w[1], w[2], w[3]);
}

// K1: bottom half. f_bot = mish(conv1(x)) rows [128,256) -> plane (b,(c-1)%16)
__global__ __launch_bounds__(256) void k1_bot(
    const float* __restrict__ x, const float* __restrict__ W1,
    const float* __restrict__ b1, ushort_t* __restrict__ shuf)
{
  int bid = blockIdx.x;          // 128 planes * 32 rowgroups
  int n   = bid >> 5;
  int rg  = bid & 31;
  int tid = threadIdx.x;
  int i   = 128 + rg*4 + (tid >> 6);
  int j0  = (tid & 63) * 4;
  const float* xp = x + (size_t)n * (H*Wd);

  float w[4][9], bb[4];
#pragma unroll
  for (int m=0;m<4;m++){
    bb[m] = b1[m];
#pragma unroll
    for (int k=0;k<9;k++) w[m][k] = W1[m*9+k];
  }

  float xv[3][6];
#pragma unroll
  for (int r=0;r<3;r++){
    int row = i-1+r;               // >=127 always
    bool rok = (row < H);
#pragma unroll
    for (int c=0;c<6;c++){
      int col = j0-1+c;
      xv[r][c] = (rok && col>=0 && col<Wd) ? xp[row*Wd+col] : 0.f;
    }
  }

  int b = n >> 4, cs = n & 15;
  int cdst = (cs + 15) & 15;
  float o[4][4];
#pragma unroll
  for (int m=0;m<4;m++){
#pragma unroll
    for (int p=0;p<4;p++){
      float s = bb[m];
#pragma unroll
      for (int ky=0;ky<3;ky++)
#pragma unroll
        for (int kx=0;kx<3;kx++)
          s = fmaf(xv[ky][p+kx], w[m][ky*3+kx], s);
      o[m][p] = mishf(s);
    }
  }
  size_t pbase = ((size_t)(b*16 + cdst))*65536 + (size_t)i*256 + j0;
#pragma unroll
  for (int p=0;p<4;p++){
    ushort4 hv;
    hv.x = f2bf(o[0][p]); hv.y = f2bf(o[1][p]);
    hv.z = f2bf(o[2][p]); hv.w = f2bf(o[3][p]);
    *(ushort4*)(shuf + (pbase + p)*4) = hv;
  }
}

// ---------------------------------------------------------------------------
// K2: top half. f_top tile in LDS (from x), g read back from shuf (f_bot was
// written by k1 -- stream order), ti = g*(Wspan (*) f_top) + (bspan (*) f_top)
// -> plane (b,c) top rows. LDS strides padded to 69 floats (odd).
// ---------------------------------------------------------------------------
__global__ __launch_bounds__(256) void k2_top(
    const float* __restrict__ x, const float* __restrict__ W1,
    const float* __restrict__ b1, const float* __restrict__ Wred,
    const float* __restrict__ bred, const float* __restrict__ Wspan,
    const float* __restrict__ bspan, ushort_t* __restrict__ shuf)
{
  __shared__ float xt[20][69];
  __shared__ float ft[4][18][69];

  int bid = blockIdx.x;             // 128 planes * 8 rowtiles * 4 coltiles
  int n   = bid >> 5;
  int t   = bid & 31;
  int itop0 = (t >> 2) * 16;
  int j0    = (t & 3) * 64;
  int tid = threadIdx.x;
  const float* xp = x + (size_t)n * (H*Wd);

  float w1r[4][9], b1r[4], wredr[4], wsp[9], bsp[9];
  float bredr = bred[0];
#pragma unroll
  for (int m=0;m<4;m++){
    b1r[m] = b1[m]; wredr[m] = Wred[m];
#pragma unroll
    for (int k=0;k<9;k++) w1r[m][k] = W1[m*9+k];
  }
#pragma unroll
  for (int k=0;k<9;k++){ wsp[k] = Wspan[k]; bsp[k] = bspan[k]; }

  for (int idx=tid; idx<20*68; idx+=256){
    int r = idx/68, c = idx - r*68;
    int row = itop0-2+r, col = j0-2+c;
    xt[r][c] = (row>=0 && col>=0 && col<Wd) ? xp[row*Wd+col] : 0.f;
  }
  __syncthreads();

  for (int idx=tid; idx<18*66; idx+=256){
    int r = idx/66, c = idx - r*66;
    int frow = itop0-1+r, fcol = j0-1+c;
    bool ok = (frow>=0 && frow<H2 && fcol<Wd && fcol>=0);
    float xv[3][3];
#pragma unroll
    for (int ky=0;ky<3;ky++)
#pragma unroll
      for (int kx=0;kx<3;kx++) xv[ky][kx] = xt[r+ky][c+kx];
#pragma unroll
    for (int m=0;m<4;m++){
      float s = b1r[m];
#pragma unroll
      for (int ky=0;ky<3;ky++)
#pragma unroll
        for (int kx=0;kx<3;kx++)
          s = fmaf(xv[ky][kx], w1r[m][ky*3+kx], s);
      ft[m][r][c] = ok ? mishf(s) : 0.f;
    }
  }
  __syncthreads();

  int lr  = tid >> 4;
  int lc4 = (tid & 15) * 4;
  int trow = itop0 + lr;
  int bq = n >> 4, cq = n & 15;

  int nb = bq*16 + ((cq + 15) & 15);
  const ushort4* fbp = (const ushort4*)(shuf +
      ((size_t)nb*65536 + (size_t)(128+trow)*256 + (j0+lc4))*4);
  float gv[4];
#pragma unroll
  for (int p=0;p<4;p++){
    ushort4 rec = fbp[p];
    float s = bredr;
    s = fmaf(bf2f(rec.x), wredr[0], s);
    s = fmaf(bf2f(rec.y), wredr[1], s);
    s = fmaf(bf2f(rec.z), wredr[2], s);
    s = fmaf(bf2f(rec.w), wredr[3], s);
    gv[p] = fmaxf(s, 0.f);
  }

  float o[4][4];
#pragma unroll
  for (int m=0;m<4;m++){
    float fv[3][6];
#pragma unroll
    for (int ky=0;ky<3;ky++)
#pragma unroll
      for (int c=0;c<6;c++)
        fv[ky][c] = ft[m][lr+ky][lc4+c];
#pragma unroll
    for (int p=0;p<4;p++){
      float A = 0.f, Bv = 0.f;
#pragma unroll
      for (int ky=0;ky<3;ky++)
#pragma unroll
        for (int kx=0;kx<3;kx++){
          A  = fmaf(fv[ky][p+kx], wsp[ky*3+kx], A);
          Bv = fmaf(fv[ky][p+kx], bsp[ky*3+kx], Bv);
        }
      o[m][p] = fmaf(gv[p], A, Bv);
    }
  }
  size_t pbase = ((size_t)(bq*16 + cq))*65536 + (size_t)trow*256 + j0 + lc4;
#pragma unroll
  for (int p=0;p<4;p++){
    ushort4 hv;
    hv.x = f2bf(o[0][p]); hv.y = f2bf(o[1][p]);
    hv.z = f2bf(o[2][p]); hv.w = f2bf(o[3][p]);
    *(ushort4*)(shuf + (pbase + p)*4) = hv;
  }
}

// ---------------------------------------------------------------------------
// K3: conv2 via MFMA implicit GEMM, no LDS staging: B fragments loaded
// directly from shuf (two coalesced 8B loads each), A fragments pre-packed.
// Block: 8x32 px tile, 4 waves = (colhalf, khalf). LDS only for khalf merge.
// XCD-swizzled grid: each XCD works one batch (shuf locality in its L2).
// ---------------------------------------------------------------------------
__global__ __launch_bounds__(256) void k3_conv2(
    const ushort_t* __restrict__ shuf, const ushort_t* __restrict__ wpack,
    const float* __restrict__ b2, float* __restrict__ scratch)
{
  __shared__ f32x4 mg[2][8][64];   // 16 KiB
  __shared__ float pacc[16];

  int bid0 = blockIdx.x;                     // 2048
  int bid  = (bid0 & 7)*256 + (bid0 >> 3);   // XCD-contiguous chunks
  int b   = bid >> 8;
  int t   = bid & 255;
  int rb  = t >> 3;
  int cb  = t & 7;
  int tid = threadIdx.x;
  int lane = tid & 63;
  int n = lane & 15;
  int g = lane >> 4;
  int wid = tid >> 6;
  int colhalf = wid & 1;
  int khalf   = wid >> 1;

  if (tid < 16) pacc[tid] = 0.f;

  // A fragments: 9 coalesced 16B loads
  const short8* wp = (const short8*)wpack + (size_t)khalf*576 + lane;
  short8 afr[9];
#pragma unroll
  for (int s = 0; s < 9; ++s) afr[s] = wp[s*64];

  f32x4 acc[8];
#pragma unroll
  for (int r = 0; r < 8; ++r) acc[r] = f32x4{0.f,0.f,0.f,0.f};

  int r0 = rb*8 - 1;
  int c  = cb*32 - 1 + colhalf*16 + n;
  int p0 = khalf*8 + g*2;                    // first of the 2 planes this lane reads
  const ushort_t* sp = shuf + ((size_t)(b*16 + p0))*262144;

#pragma unroll
  for (int hr = 0; hr < 10; ++hr){
    int grow = r0 + hr;
    bool rok = (unsigned)grow < 256u;
    uint2 va[3], vb[3];
#pragma unroll
    for (int kx = 0; kx < 3; ++kx){
      int gcol = c + kx;
      uint2 a = make_uint2(0u,0u), bv = make_uint2(0u,0u);
      if (rok && (unsigned)gcol < 256u){
        const ushort_t* pp = sp + (size_t)(grow*256 + gcol)*4;
        a  = *(const uint2*)pp;
        bv = *(const uint2*)(pp + 262144);
      }
      va[kx] = a; vb[kx] = bv;
    }
#pragma unroll
    for (int kx = 0; kx < 3; ++kx){
      union { uint4 u; short8 s; } cv;
      cv.u = make_uint4(va[kx].x, va[kx].y, vb[kx].x, vb[kx].y);
#pragma unroll
      for (int ky = 0; ky < 3; ++ky){
        int orow = hr - ky;
        if (orow >= 0 && orow < 8){
          acc[orow] = __builtin_amdgcn_mfma_f32_16x16x32_bf16(
              afr[ky*3+kx], cv.s, acc[orow], 0, 0, 0);
        }
      }
    }
  }

  // merge khalf partials via LDS
  if (khalf == 1){
#pragma unroll
    for (int r = 0; r < 8; ++r) mg[colhalf][r][lane] = acc[r];
  }
  __syncthreads();

  if (khalf == 0){
    float b2v[4];
#pragma unroll
    for (int q = 0; q < 4; ++q) b2v[q] = b2[g*4 + q];
    float po[4] = {0.f, 0.f, 0.f, 0.f};
#pragma unroll
    for (int r = 0; r < 8; ++r){
      f32x4 o = acc[r] + mg[colhalf][r][lane];
#pragma unroll
      for (int q = 0; q < 4; ++q) po[q] += mishf(o[q] + b2v[q]);
    }
#pragma unroll
    for (int q = 0; q < 4; ++q){
#pragma unroll
      for (int mk = 1; mk < 16; mk <<= 1) po[q] += __shfl_xor(po[q], mk);
    }
    if (n == 0){
#pragma unroll
      for (int q = 0; q < 4; ++q) atomicAdd(&pacc[g*4 + q], po[q]);
    }
  }
  __syncthreads();
  if (tid < 16) scratch[bid*16 + tid] = pacc[tid];
}

// K4: reduce per-block partials -> pooled mean -> ECA gate. One block per b.
__global__ void k4_gate(const float* __restrict__ scratch,
                        const float* __restrict__ Weca,
                        float* __restrict__ gate)
{
  __shared__ float rr[16][16];
  __shared__ float pool[16];
  int b = blockIdx.x;
  int t = threadIdx.x;           // 256
  int oc = t & 15, ch = t >> 4;
  float s = 0.f;
  for (int u = 0; u < 16; ++u)
    s += scratch[(size_t)(b*256 + ch*16 + u)*16 + oc];
  rr[ch][oc] = s;
  __syncthreads();
  if (t < 16){
    float tot = 0.f;
#pragma unroll
    for (int k = 0; k < 16; ++k) tot += rr[k][t];
    pool[t] = tot * (1.0f/65536.0f);
  }
  __syncthreads();
  if (t < 16){
    float pm = (t > 0)  ? pool[t-1] : 0.f;
    float p0 = pool[t];
    float pp = (t < 15) ? pool[t+1] : 0.f;
    float z = Weca[0]*pm + Weca[1]*p0 + Weca[2]*pp;
    gate[b*16 + t] = 1.f/(1.f + __expf(-z));
  }
}

// K5: out = x * gate[b,c]
__global__ __launch_bounds__(256) void k5_scale(
    const float4* __restrict__ x4, const float* __restrict__ gate,
    float4* __restrict__ out4)
{
  int idx = blockIdx.x*256 + threadIdx.x;
  float g = gate[idx >> 14];
  float4 v = x4[idx];
  v.x *= g; v.y *= g; v.z *= g; v.w *= g;
  out4[idx] = v;
}

extern "C" void kernel_launch(void* const* d_in, const int* in_sizes, int n_in,
                              void* d_out, int out_size, void* d_ws, size_t ws_size,
                              hipStream_t stream)
{
  const float* x     = (const float*)d_in[0];
  const float* W1    = (const float*)d_in[1];
  const float* b1    = (const float*)d_in[2];
  const float* Wred  = (const float*)d_in[3];
  const float* bred  = (const float*)d_in[4];
  const float* Wspan = (const float*)d_in[5];
  const float* bspan = (const float*)d_in[6];
  const float* W2    = (const float*)d_in[7];
  const float* b2    = (const float*)d_in[8];
  const float* Weca  = (const float*)d_in[9];

  ushort_t* shuf    = (ushort_t*)d_ws;                        // 64 MiB records
  float*    gate    = (float*)((char*)d_ws + 67108864);       // 512 B
  ushort_t* wpack   = (ushort_t*)((char*)d_ws + 67108864 + 1024); // 18.4 KiB
  float*    scratch = (float*)d_out;  // 2048*16 floats; overwritten by k5

  k0_pack<<<9, 128, 0, stream>>>(W2, wpack);
  k1_bot <<<4096, 256, 0, stream>>>(x, W1, b1, shuf);
  k2_top <<<4096, 256, 0, stream>>>(x, W1, b1, Wred, bred, Wspan, bspan, shuf);
  k3_conv2<<<2048, 256, 0, stream>>>(shuf, wpack, b2, scratch);
  k4_gate<<<8, 256, 0, stream>>>(scratch, Weca, gate);
  k5_scale<<<8192, 256, 0, stream>>>((const float4*)x, gate, (float4*)d_out);
}

// Round 5
// 90.606 us; speedup vs baseline: 3.6380x; 1.0954x over previous
//
#include <hip/hip_runtime.h>
#include <hip/hip_bf16.h>

#define H 256
#define Wd 256
#define H2 128

typedef unsigned short ushort_t;
typedef __attribute__((ext_vector_type(8))) short short8;
typedef __attribute__((ext_vector_type(4))) float f32x4;
typedef __attribute__((ext_vector_type(2))) float f32x2;

__device__ __forceinline__ float mishf(float v){
  if (v > 15.f) return v;
  float e = __expf(v);
  float w = e*(e+2.f);
  return v * w * __builtin_amdgcn_rcpf(w + 2.f);
}

__device__ __forceinline__ ushort_t f2bf(float f){
  unsigned int u = __float_as_uint(f);
  u += 0x7fffu + ((u >> 16) & 1u);
  return (ushort_t)(u >> 16);
}
__device__ __forceinline__ float bf2f(ushort_t h){
  return __uint_as_float(((unsigned int)h) << 16);
}

// ---------------------------------------------------------------------------
// shuf layout: 8-byte pixel records  [plane = b*16 + c][i*256 + j][m0..3]
// (bf16 x4). k12 writes top rows (own plane) and bottom rows (rolled plane).
// ---------------------------------------------------------------------------

// K0: pre-pack W2 into bf16 MFMA A-fragment order (as round 4).
__global__ void k0_pack(const float* __restrict__ W2, ushort_t* __restrict__ wpack)
{
  int idx = blockIdx.x*128 + threadIdx.x;   // 0..1151
  if (idx >= 1152) return;
  int lane  = idx & 63;
  int s     = (idx >> 6) % 9;
  int khalf = idx / 576;
  int n = lane & 15, g = lane >> 4;
  unsigned int w[4];
#pragma unroll
  for (int h = 0; h < 4; ++h){
    int ch0 = khalf*32 + g*8 + 2*h;
    unsigned lo = f2bf(W2[(n*64 + ch0  )*9 + s]);
    unsigned hi = f2bf(W2[(n*64 + ch0+1)*9 + s]);
    w[h] = lo | (hi << 16);
  }
  *(uint4*)(wpack + (size_t)idx*8) = make_uint4(w[0], w[1], w[2], w[3]);
}

// ---------------------------------------------------------------------------
// K12: fused conv1 top+bottom for one (plane, 16x64 tile).
//  - f_top tile in LDS (conv1+mish from staged x_top), strides 69 (2-way free)
//  - f_bot for the tile's own rows in REGISTERS (from staged x_bot)
//    -> written to rolled plane bottom, and used fp32 for g = relu(Wred.f_bot)
//  - ti = g*(Wspan (*) f_top) + (bspan (*) f_top) -> own plane top rows
//  - packed-f32 (v_pk_fma_f32) accumulation for conv1 (m-pairs) and span (A,B)
// ---------------------------------------------------------------------------
__global__ __launch_bounds__(256) void k12(
    const float* __restrict__ x, const float* __restrict__ W1,
    const float* __restrict__ b1, const float* __restrict__ Wred,
    const float* __restrict__ bred, const float* __restrict__ Wspan,
    const float* __restrict__ bspan, ushort_t* __restrict__ shuf)
{
  __shared__ float xt[20][69];      // x rows itop0-2..itop0+17, cols j0-2..j0+65
  __shared__ float xb[18][69];      // x rows 127+itop0..144+itop0, same cols
  __shared__ float ft[4][18][69];   // f_top rows itop0-1..itop0+16, cols j0-1..j0+64

  int bid = blockIdx.x;             // 128 planes * 8 rowtiles * 4 coltiles
  int n   = bid >> 5;
  int t   = bid & 31;
  int itop0 = (t >> 2) * 16;
  int j0    = (t & 3) * 64;
  int tid = threadIdx.x;
  const float* xp = x + (size_t)n * (H*Wd);

  // weights: conv1 as m-pair packed, span as (A,B) packed
  f32x2 w01[9], w23[9], b01, b23, wspb[9];
  float wredr[4];
  float bredr = bred[0];
#pragma unroll
  for (int k=0;k<9;k++){
    w01[k] = f32x2{W1[k], W1[9+k]};
    w23[k] = f32x2{W1[18+k], W1[27+k]};
    wspb[k] = f32x2{Wspan[k], bspan[k]};
  }
  b01 = f32x2{b1[0], b1[1]};
  b23 = f32x2{b1[2], b1[3]};
#pragma unroll
  for (int m=0;m<4;m++) wredr[m] = Wred[m];

  // stage x_top and x_bot (scalar dword, coalesced, stride-69 rows)
  for (int idx=tid; idx<20*68; idx+=256){
    int r = idx/68, c = idx - r*68;
    int row = itop0-2+r, col = j0-2+c;
    xt[r][c] = (row>=0 && col>=0 && col<Wd) ? xp[row*Wd+col] : 0.f;
  }
  for (int idx=tid; idx<18*68; idx+=256){
    int r = idx/68, c = idx - r*68;
    int row = 127+itop0+r, col = j0-2+c;
    xb[r][c] = (row<H && col>=0 && col<Wd) ? xp[row*Wd+col] : 0.f;
  }
  __syncthreads();

  // f_top into LDS (all 4 m per element), packed conv1
  for (int idx=tid; idx<18*66; idx+=256){
    int r = idx/66, c = idx - r*66;
    int frow = itop0-1+r, fcol = j0-1+c;
    bool ok = (frow>=0 && frow<H2 && fcol>=0 && fcol<Wd);
    f32x2 s01 = b01, s23 = b23;
#pragma unroll
    for (int ky=0;ky<3;ky++)
#pragma unroll
      for (int kx=0;kx<3;kx++){
        float xv = xt[r+ky][c+kx];
        f32x2 xv2 = f32x2{xv, xv};
        s01 = xv2*w01[ky*3+kx] + s01;
        s23 = xv2*w23[ky*3+kx] + s23;
      }
    ft[0][r][c] = ok ? mishf(s01.x) : 0.f;
    ft[1][r][c] = ok ? mishf(s01.y) : 0.f;
    ft[2][r][c] = ok ? mishf(s23.x) : 0.f;
    ft[3][r][c] = ok ? mishf(s23.y) : 0.f;
  }

  int lr  = tid >> 4;
  int lc4 = (tid & 15) * 4;
  int trow = itop0 + lr;
  int bq = n >> 4, cq = n & 15;

  // f_bot for own 4 px in registers (packed conv1), store rolled + compute g
  float fb[4][4];   // [m][p]
  {
    float xv[3][6];
#pragma unroll
    for (int r=0;r<3;r++)
#pragma unroll
      for (int c=0;c<6;c++)
        xv[r][c] = xb[lr+r][lc4+1+c];   // x col = j0+lc4-1+c
#pragma unroll
    for (int p=0;p<4;p++){
      f32x2 s01 = b01, s23 = b23;
#pragma unroll
      for (int ky=0;ky<3;ky++)
#pragma unroll
        for (int kx=0;kx<3;kx++){
          float v = xv[ky][p+kx];
          f32x2 v2 = f32x2{v, v};
          s01 = v2*w01[ky*3+kx] + s01;
          s23 = v2*w23[ky*3+kx] + s23;
        }
      fb[0][p] = mishf(s01.x); fb[1][p] = mishf(s01.y);
      fb[2][p] = mishf(s23.x); fb[3][p] = mishf(s23.y);
    }
  }
  int cdst = (cq + 15) & 15;
  size_t bbase = ((size_t)(bq*16 + cdst))*65536 + (size_t)(128+trow)*256 + j0 + lc4;
#pragma unroll
  for (int p=0;p<4;p++){
    ushort4 hv;
    hv.x = f2bf(fb[0][p]); hv.y = f2bf(fb[1][p]);
    hv.z = f2bf(fb[2][p]); hv.w = f2bf(fb[3][p]);
    *(ushort4*)(shuf + (bbase + p)*4) = hv;
  }
  float gv[4];
#pragma unroll
  for (int p=0;p<4;p++){
    float s = bredr;
#pragma unroll
    for (int m=0;m<4;m++) s = fmaf(fb[m][p], wredr[m], s);
    gv[p] = fmaxf(s, 0.f);
  }

  __syncthreads();

  // span convs (A,B packed) + gate + store top
  float o[4][4];
#pragma unroll
  for (int m=0;m<4;m++){
    float fv[3][6];
#pragma unroll
    for (int ky=0;ky<3;ky++)
#pragma unroll
      for (int c=0;c<6;c++)
        fv[ky][c] = ft[m][lr+ky][lc4+c];
#pragma unroll
    for (int p=0;p<4;p++){
      f32x2 ab = f32x2{0.f, 0.f};
#pragma unroll
      for (int ky=0;ky<3;ky++)
#pragma unroll
        for (int kx=0;kx<3;kx++){
          float fvv = fv[ky][p+kx];
          ab = f32x2{fvv, fvv}*wspb[ky*3+kx] + ab;
        }
      o[m][p] = fmaf(gv[p], ab.x, ab.y);
    }
  }
  size_t pbase = ((size_t)(bq*16 + cq))*65536 + (size_t)trow*256 + j0 + lc4;
#pragma unroll
  for (int p=0;p<4;p++){
    ushort4 hv;
    hv.x = f2bf(o[0][p]); hv.y = f2bf(o[1][p]);
    hv.z = f2bf(o[2][p]); hv.w = f2bf(o[3][p]);
    *(ushort4*)(shuf + (pbase + p)*4) = hv;
  }
}

// ---------------------------------------------------------------------------
// K3: conv2 via MFMA implicit GEMM, direct-from-global B fragments (round 4).
// ---------------------------------------------------------------------------
__global__ __launch_bounds__(256) void k3_conv2(
    const ushort_t* __restrict__ shuf, const ushort_t* __restrict__ wpack,
    const float* __restrict__ b2, float* __restrict__ scratch)
{
  __shared__ f32x4 mg[2][8][64];   // 16 KiB
  __shared__ float pacc[16];

  int bid0 = blockIdx.x;                     // 2048
  int bid  = (bid0 & 7)*256 + (bid0 >> 3);   // XCD-contiguous chunks
  int b   = bid >> 8;
  int t   = bid & 255;
  int rb  = t >> 3;
  int cb  = t & 7;
  int tid = threadIdx.x;
  int lane = tid & 63;
  int n = lane & 15;
  int g = lane >> 4;
  int wid = tid >> 6;
  int colhalf = wid & 1;
  int khalf   = wid >> 1;

  if (tid < 16) pacc[tid] = 0.f;

  const short8* wp = (const short8*)wpack + (size_t)khalf*576 + lane;
  short8 afr[9];
#pragma unroll
  for (int s = 0; s < 9; ++s) afr[s] = wp[s*64];

  f32x4 acc[8];
#pragma unroll
  for (int r = 0; r < 8; ++r) acc[r] = f32x4{0.f,0.f,0.f,0.f};

  int r0 = rb*8 - 1;
  int c  = cb*32 - 1 + colhalf*16 + n;
  int p0 = khalf*8 + g*2;
  const ushort_t* sp = shuf + ((size_t)(b*16 + p0))*262144;

#pragma unroll
  for (int hr = 0; hr < 10; ++hr){
    int grow = r0 + hr;
    bool rok = (unsigned)grow < 256u;
    uint2 va[3], vb[3];
#pragma unroll
    for (int kx = 0; kx < 3; ++kx){
      int gcol = c + kx;
      uint2 a = make_uint2(0u,0u), bv = make_uint2(0u,0u);
      if (rok && (unsigned)gcol < 256u){
        const ushort_t* pp = sp + (size_t)(grow*256 + gcol)*4;
        a  = *(const uint2*)pp;
        bv = *(const uint2*)(pp + 262144);
      }
      va[kx] = a; vb[kx] = bv;
    }
#pragma unroll
    for (int kx = 0; kx < 3; ++kx){
      union { uint4 u; short8 s; } cv;
      cv.u = make_uint4(va[kx].x, va[kx].y, vb[kx].x, vb[kx].y);
#pragma unroll
      for (int ky = 0; ky < 3; ++ky){
        int orow = hr - ky;
        if (orow >= 0 && orow < 8){
          acc[orow] = __builtin_amdgcn_mfma_f32_16x16x32_bf16(
              afr[ky*3+kx], cv.s, acc[orow], 0, 0, 0);
        }
      }
    }
  }

  if (khalf == 1){
#pragma unroll
    for (int r = 0; r < 8; ++r) mg[colhalf][r][lane] = acc[r];
  }
  __syncthreads();

  if (khalf == 0){
    float b2v[4];
#pragma unroll
    for (int q = 0; q < 4; ++q) b2v[q] = b2[g*4 + q];
    float po[4] = {0.f, 0.f, 0.f, 0.f};
#pragma unroll
    for (int r = 0; r < 8; ++r){
      f32x4 o = acc[r] + mg[colhalf][r][lane];
#pragma unroll
      for (int q = 0; q < 4; ++q) po[q] += mishf(o[q] + b2v[q]);
    }
#pragma unroll
    for (int q = 0; q < 4; ++q){
#pragma unroll
      for (int mk = 1; mk < 16; mk <<= 1) po[q] += __shfl_xor(po[q], mk);
    }
    if (n == 0){
#pragma unroll
      for (int q = 0; q < 4; ++q) atomicAdd(&pacc[g*4 + q], po[q]);
    }
  }
  __syncthreads();
  if (tid < 16) scratch[bid*16 + tid] = pacc[tid];
}

// K4: reduce per-block partials -> pooled mean -> ECA gate. One block per b.
__global__ void k4_gate(const float* __restrict__ scratch,
                        const float* __restrict__ Weca,
                        float* __restrict__ gate)
{
  __shared__ float rr[16][16];
  __shared__ float pool[16];
  int b = blockIdx.x;
  int t = threadIdx.x;           // 256
  int oc = t & 15, ch = t >> 4;
  float s = 0.f;
  for (int u = 0; u < 16; ++u)
    s += scratch[(size_t)(b*256 + ch*16 + u)*16 + oc];
  rr[ch][oc] = s;
  __syncthreads();
  if (t < 16){
    float tot = 0.f;
#pragma unroll
    for (int k = 0; k < 16; ++k) tot += rr[k][t];
    pool[t] = tot * (1.0f/65536.0f);
  }
  __syncthreads();
  if (t < 16){
    float pm = (t > 0)  ? pool[t-1] : 0.f;
    float p0 = pool[t];
    float pp = (t < 15) ? pool[t+1] : 0.f;
    float z = Weca[0]*pm + Weca[1]*p0 + Weca[2]*pp;
    gate[b*16 + t] = 1.f/(1.f + __expf(-z));
  }
}

// K5: out = x * gate[b,c], nontemporal stores (out never re-read; keep x in L3)
__global__ __launch_bounds__(256) void k5_scale(
    const f32x4* __restrict__ x4, const float* __restrict__ gate,
    f32x4* __restrict__ out4)
{
  int idx = blockIdx.x*256 + threadIdx.x;
  float g = gate[idx >> 14];
  f32x4 v = x4[idx] * g;
  __builtin_nontemporal_store(v, &out4[idx]);
}

extern "C" void kernel_launch(void* const* d_in, const int* in_sizes, int n_in,
                              void* d_out, int out_size, void* d_ws, size_t ws_size,
                              hipStream_t stream)
{
  const float* x     = (const float*)d_in[0];
  const float* W1    = (const float*)d_in[1];
  const float* b1    = (const float*)d_in[2];
  const float* Wred  = (const float*)d_in[3];
  const float* bred  = (const float*)d_in[4];
  const float* Wspan = (const float*)d_in[5];
  const float* bspan = (const float*)d_in[6];
  const float* W2    = (const float*)d_in[7];
  const float* b2    = (const float*)d_in[8];
  const float* Weca  = (const float*)d_in[9];

  ushort_t* shuf    = (ushort_t*)d_ws;                        // 64 MiB records
  float*    gate    = (float*)((char*)d_ws + 67108864);       // 512 B
  ushort_t* wpack   = (ushort_t*)((char*)d_ws + 67108864 + 1024); // 18.4 KiB
  float*    scratch = (float*)d_out;  // 2048*16 floats; overwritten by k5

  k0_pack<<<9, 128, 0, stream>>>(W2, wpack);
  k12    <<<4096, 256, 0, stream>>>(x, W1, b1, Wred, bred, Wspan, bspan, shuf);
  k3_conv2<<<2048, 256, 0, stream>>>(shuf, wpack, b2, scratch);
  k4_gate<<<8, 256, 0, stream>>>(scratch, Weca, gate);
  k5_scale<<<8192, 256, 0, stream>>>((const f32x4*)x, gate, (f32x4*)d_out);
}

// Round 6
// 85.449 us; speedup vs baseline: 3.8576x; 1.0604x over previous
//
#include <hip/hip_runtime.h>
#include <hip/hip_bf16.h>

#define H 256
#define Wd 256
#define H2 128

typedef unsigned short ushort_t;
typedef __attribute__((ext_vector_type(8))) short short8;
typedef __attribute__((ext_vector_type(4))) float f32x4;
typedef __attribute__((ext_vector_type(2))) float f32x2;

__device__ __forceinline__ float mishf(float v){
  if (v > 15.f) return v;
  float e = __expf(v);
  float w = e*(e+2.f);
  return v * w * __builtin_amdgcn_rcpf(w + 2.f);
}

__device__ __forceinline__ ushort_t f2bf(float f){
  unsigned int u = __float_as_uint(f);
  u += 0x7fffu + ((u >> 16) & 1u);
  return (ushort_t)(u >> 16);
}
__device__ __forceinline__ float bf2f(ushort_t h){
  return __uint_as_float(((unsigned int)h) << 16);
}
__device__ __forceinline__ unsigned packbf(float a, float b){
  return (unsigned)f2bf(a) | ((unsigned)f2bf(b) << 16);
}
__device__ __forceinline__ float lo16(unsigned u){
  return __uint_as_float(u << 16);
}
__device__ __forceinline__ float hi16(unsigned u){
  return __uint_as_float(u & 0xffff0000u);
}

// ---------------------------------------------------------------------------
// shuf layout: 8-byte pixel records  [plane = b*16 + c][i*256 + j][m0..3]
// (bf16 x4). k12 writes top rows (own plane) and bottom rows (rolled plane).
// ---------------------------------------------------------------------------

// K0: pre-pack W2 into bf16 MFMA A-fragment order.
__global__ void k0_pack(const float* __restrict__ W2, ushort_t* __restrict__ wpack)
{
  int idx = blockIdx.x*128 + threadIdx.x;   // 0..1151
  if (idx >= 1152) return;
  int lane  = idx & 63;
  int s     = (idx >> 6) % 9;
  int khalf = idx / 576;
  int n = lane & 15, g = lane >> 4;
  unsigned int w[4];
#pragma unroll
  for (int h = 0; h < 4; ++h){
    int ch0 = khalf*32 + g*8 + 2*h;
    unsigned lo = f2bf(W2[(n*64 + ch0  )*9 + s]);
    unsigned hi = f2bf(W2[(n*64 + ch0+1)*9 + s]);
    w[h] = lo | (hi << 16);
  }
  *(uint4*)(wpack + (size_t)idx*8) = make_uint4(w[0], w[1], w[2], w[3]);
}

// ---------------------------------------------------------------------------
// K12: fused conv1 top+bottom for one (plane, 16x64 tile).
//  - x staged with float4 loads; LDS rows odd-stride 73 (bank-spread for the
//    (tid&15)*4 column pattern -- even strides collapse to 8-way conflicts)
//  - f_top in LDS as packed bf16 m-pairs (halves LDS + span reads)
//  - f_bot in registers -> rolled-plane bottom store + g = relu(Wred.f_bot)
//  - ti = g*(Wspan (*) f_top) + (bspan (*) f_top) -> own plane top rows
// ---------------------------------------------------------------------------
__global__ __launch_bounds__(256) void k12(
    const float* __restrict__ x, const float* __restrict__ W1,
    const float* __restrict__ b1, const float* __restrict__ Wred,
    const float* __restrict__ bred, const float* __restrict__ Wspan,
    const float* __restrict__ bspan, ushort_t* __restrict__ shuf)
{
  __shared__ float xt[20][73];       // x rows itop0-2..+17, cols j0-4..j0+67
  __shared__ float xb[18][73];       // x rows 127+itop0..+17, cols j0-4..j0+67
  __shared__ unsigned ftp[2][18][69];// packed bf16 (m0|m1, m2|m3), rows itop0-1..+16, cols j0-1..+64

  int bid = blockIdx.x;             // 128 planes * 8 rowtiles * 4 coltiles
  int n   = bid >> 5;
  int t   = bid & 31;
  int itop0 = (t >> 2) * 16;
  int j0    = (t & 3) * 64;
  int tid = threadIdx.x;
  const float* xp = x + (size_t)n * (H*Wd);

  f32x2 w01[9], w23[9], b01, b23, wspb[9];
  float wredr[4];
  float bredr = bred[0];
#pragma unroll
  for (int k=0;k<9;k++){
    w01[k] = f32x2{W1[k], W1[9+k]};
    w23[k] = f32x2{W1[18+k], W1[27+k]};
    wspb[k] = f32x2{Wspan[k], bspan[k]};
  }
  b01 = f32x2{b1[0], b1[1]};
  b23 = f32x2{b1[2], b1[3]};
#pragma unroll
  for (int m=0;m<4;m++) wredr[m] = Wred[m];

  // ---- stage x_top: 20 rows x 18 float4 (cols j0-4 .. j0+67) ----
  for (int idx=tid; idx<360; idx+=256){
    int r = idx/18, q = idx - r*18;
    int grow = itop0-2+r, gcol = j0-4+q*4;
    float4 v = make_float4(0.f,0.f,0.f,0.f);
    if (grow>=0 && gcol>=0 && gcol<Wd)
      v = *(const float4*)(xp + (size_t)grow*Wd + gcol);
    int c0 = q*4;
    xt[r][c0] = v.x; xt[r][c0+1] = v.y; xt[r][c0+2] = v.z; xt[r][c0+3] = v.w;
  }
  // ---- stage x_bot: 18 rows x 18 float4 ----
  for (int idx=tid; idx<324; idx+=256){
    int r = idx/18, q = idx - r*18;
    int grow = 127+itop0+r, gcol = j0-4+q*4;
    float4 v = make_float4(0.f,0.f,0.f,0.f);
    if (grow<H && gcol>=0 && gcol<Wd)
      v = *(const float4*)(xp + (size_t)grow*Wd + gcol);
    int c0 = q*4;
    xb[r][c0] = v.x; xb[r][c0+1] = v.y; xb[r][c0+2] = v.z; xb[r][c0+3] = v.w;
  }
  __syncthreads();

  // ---- f_top -> packed bf16 LDS (18 x 66 elements) ----
  for (int idx=tid; idx<18*66; idx+=256){
    int r = idx/66, c = idx - r*66;
    int frow = itop0-1+r, fcol = j0-1+c;
    unsigned u01 = 0u, u23 = 0u;
    if (frow>=0 && frow<H2 && fcol>=0 && fcol<Wd){
      f32x2 s01 = b01, s23 = b23;
#pragma unroll
      for (int ky=0;ky<3;ky++)
#pragma unroll
        for (int kx=0;kx<3;kx++){
          float xv = xt[r+ky][c+kx+2];
          f32x2 xv2 = f32x2{xv, xv};
          s01 = xv2*w01[ky*3+kx] + s01;
          s23 = xv2*w23[ky*3+kx] + s23;
        }
      u01 = packbf(mishf(s01.x), mishf(s01.y));
      u23 = packbf(mishf(s23.x), mishf(s23.y));
    }
    ftp[0][r][c] = u01;
    ftp[1][r][c] = u23;
  }

  int lr  = tid >> 4;
  int lc4 = (tid & 15) * 4;
  int trow = itop0 + lr;
  int bq = n >> 4, cq = n & 15;

  // ---- f_bot own 4 px in registers ----
  float fb[4][4];   // [m][p]
  {
    float xv[3][6];
#pragma unroll
    for (int r=0;r<3;r++)
#pragma unroll
      for (int c=0;c<6;c++)
        xv[r][c] = xb[lr+r][lc4+3+c];
#pragma unroll
    for (int p=0;p<4;p++){
      f32x2 s01 = b01, s23 = b23;
#pragma unroll
      for (int ky=0;ky<3;ky++)
#pragma unroll
        for (int kx=0;kx<3;kx++){
          float v = xv[ky][p+kx];
          f32x2 v2 = f32x2{v, v};
          s01 = v2*w01[ky*3+kx] + s01;
          s23 = v2*w23[ky*3+kx] + s23;
        }
      fb[0][p] = mishf(s01.x); fb[1][p] = mishf(s01.y);
      fb[2][p] = mishf(s23.x); fb[3][p] = mishf(s23.y);
    }
  }
  // bottom store (rolled plane), 2 px per dwordx4
  int cdst = (cq + 15) & 15;
  size_t bbase = ((size_t)(bq*16 + cdst))*65536 + (size_t)(128+trow)*256 + j0 + lc4;
  {
    unsigned w0 = packbf(fb[0][0], fb[1][0]), w1 = packbf(fb[2][0], fb[3][0]);
    unsigned w2 = packbf(fb[0][1], fb[1][1]), w3 = packbf(fb[2][1], fb[3][1]);
    *(uint4*)(shuf + bbase*4) = make_uint4(w0,w1,w2,w3);
    unsigned w4 = packbf(fb[0][2], fb[1][2]), w5 = packbf(fb[2][2], fb[3][2]);
    unsigned w6 = packbf(fb[0][3], fb[1][3]), w7 = packbf(fb[2][3], fb[3][3]);
    *(uint4*)(shuf + (bbase+2)*4) = make_uint4(w4,w5,w6,w7);
  }
  float gv[4];
#pragma unroll
  for (int p=0;p<4;p++){
    float s = bredr;
#pragma unroll
    for (int m=0;m<4;m++) s = fmaf(fb[m][p], wredr[m], s);
    gv[p] = fmaxf(s, 0.f);
  }

  __syncthreads();

  // ---- span convs from packed ft + gate + top store ----
  unsigned fv0[3][6], fv1[3][6];
#pragma unroll
  for (int ky=0;ky<3;ky++)
#pragma unroll
    for (int c=0;c<6;c++){
      fv0[ky][c] = ftp[0][lr+ky][lc4+c];
      fv1[ky][c] = ftp[1][lr+ky][lc4+c];
    }

  float o[4][4];
#pragma unroll
  for (int p=0;p<4;p++){
    f32x2 ab0 = f32x2{0.f,0.f}, ab1 = ab0, ab2 = ab0, ab3 = ab0;
#pragma unroll
    for (int ky=0;ky<3;ky++)
#pragma unroll
      for (int kx=0;kx<3;kx++){
        f32x2 w = wspb[ky*3+kx];
        unsigned u0 = fv0[ky][p+kx], u1 = fv1[ky][p+kx];
        float a = lo16(u0), b = hi16(u0), c2 = lo16(u1), d = hi16(u1);
        ab0 = f32x2{a,a}*w + ab0;
        ab1 = f32x2{b,b}*w + ab1;
        ab2 = f32x2{c2,c2}*w + ab2;
        ab3 = f32x2{d,d}*w + ab3;
      }
    o[0][p] = fmaf(gv[p], ab0.x, ab0.y);
    o[1][p] = fmaf(gv[p], ab1.x, ab1.y);
    o[2][p] = fmaf(gv[p], ab2.x, ab2.y);
    o[3][p] = fmaf(gv[p], ab3.x, ab3.y);
  }
  size_t pbase = ((size_t)(bq*16 + cq))*65536 + (size_t)trow*256 + j0 + lc4;
  {
    unsigned w0 = packbf(o[0][0], o[1][0]), w1 = packbf(o[2][0], o[3][0]);
    unsigned w2 = packbf(o[0][1], o[1][1]), w3 = packbf(o[2][1], o[3][1]);
    *(uint4*)(shuf + pbase*4) = make_uint4(w0,w1,w2,w3);
    unsigned w4 = packbf(o[0][2], o[1][2]), w5 = packbf(o[2][2], o[3][2]);
    unsigned w6 = packbf(o[0][3], o[1][3]), w7 = packbf(o[2][3], o[3][3]);
    *(uint4*)(shuf + (pbase+2)*4) = make_uint4(w4,w5,w6,w7);
  }
}

// ---------------------------------------------------------------------------
// K3: conv2 via MFMA implicit GEMM, direct-from-global B fragments.
// ---------------------------------------------------------------------------
__global__ __launch_bounds__(256) void k3_conv2(
    const ushort_t* __restrict__ shuf, const ushort_t* __restrict__ wpack,
    const float* __restrict__ b2, float* __restrict__ scratch)
{
  __shared__ f32x4 mg[2][8][64];   // 16 KiB
  __shared__ float pacc[16];

  int bid0 = blockIdx.x;                     // 2048
  int bid  = (bid0 & 7)*256 + (bid0 >> 3);   // XCD-contiguous chunks
  int b   = bid >> 8;
  int t   = bid & 255;
  int rb  = t >> 3;
  int cb  = t & 7;
  int tid = threadIdx.x;
  int lane = tid & 63;
  int n = lane & 15;
  int g = lane >> 4;
  int wid = tid >> 6;
  int colhalf = wid & 1;
  int khalf   = wid >> 1;

  if (tid < 16) pacc[tid] = 0.f;

  const short8* wp = (const short8*)wpack + (size_t)khalf*576 + lane;
  short8 afr[9];
#pragma unroll
  for (int s = 0; s < 9; ++s) afr[s] = wp[s*64];

  f32x4 acc[8];
#pragma unroll
  for (int r = 0; r < 8; ++r) acc[r] = f32x4{0.f,0.f,0.f,0.f};

  int r0 = rb*8 - 1;
  int c  = cb*32 - 1 + colhalf*16 + n;
  int p0 = khalf*8 + g*2;
  const ushort_t* sp = shuf + ((size_t)(b*16 + p0))*262144;

#pragma unroll
  for (int hr = 0; hr < 10; ++hr){
    int grow = r0 + hr;
    bool rok = (unsigned)grow < 256u;
    uint2 va[3], vb[3];
#pragma unroll
    for (int kx = 0; kx < 3; ++kx){
      int gcol = c + kx;
      uint2 a = make_uint2(0u,0u), bv = make_uint2(0u,0u);
      if (rok && (unsigned)gcol < 256u){
        const ushort_t* pp = sp + (size_t)(grow*256 + gcol)*4;
        a  = *(const uint2*)pp;
        bv = *(const uint2*)(pp + 262144);
      }
      va[kx] = a; vb[kx] = bv;
    }
#pragma unroll
    for (int kx = 0; kx < 3; ++kx){
      union { uint4 u; short8 s; } cv;
      cv.u = make_uint4(va[kx].x, va[kx].y, vb[kx].x, vb[kx].y);
#pragma unroll
      for (int ky = 0; ky < 3; ++ky){
        int orow = hr - ky;
        if (orow >= 0 && orow < 8){
          acc[orow] = __builtin_amdgcn_mfma_f32_16x16x32_bf16(
              afr[ky*3+kx], cv.s, acc[orow], 0, 0, 0);
        }
      }
    }
  }

  if (khalf == 1){
#pragma unroll
    for (int r = 0; r < 8; ++r) mg[colhalf][r][lane] = acc[r];
  }
  __syncthreads();

  if (khalf == 0){
    float b2v[4];
#pragma unroll
    for (int q = 0; q < 4; ++q) b2v[q] = b2[g*4 + q];
    float po[4] = {0.f, 0.f, 0.f, 0.f};
#pragma unroll
    for (int r = 0; r < 8; ++r){
      f32x4 o = acc[r] + mg[colhalf][r][lane];
#pragma unroll
      for (int q = 0; q < 4; ++q) po[q] += mishf(o[q] + b2v[q]);
    }
#pragma unroll
    for (int q = 0; q < 4; ++q){
#pragma unroll
      for (int mk = 1; mk < 16; mk <<= 1) po[q] += __shfl_xor(po[q], mk);
    }
    if (n == 0){
#pragma unroll
      for (int q = 0; q < 4; ++q) atomicAdd(&pacc[g*4 + q], po[q]);
    }
  }
  __syncthreads();
  if (tid < 16) scratch[bid*16 + tid] = pacc[tid];
}

// K4: reduce per-block partials -> pooled mean -> ECA gate. One block per b.
__global__ void k4_gate(const float* __restrict__ scratch,
                        const float* __restrict__ Weca,
                        float* __restrict__ gate)
{
  __shared__ float rr[16][16];
  __shared__ float pool[16];
  int b = blockIdx.x;
  int t = threadIdx.x;           // 256
  int oc = t & 15, ch = t >> 4;
  float s = 0.f;
  for (int u = 0; u < 16; ++u)
    s += scratch[(size_t)(b*256 + ch*16 + u)*16 + oc];
  rr[ch][oc] = s;
  __syncthreads();
  if (t < 16){
    float tot = 0.f;
#pragma unroll
    for (int k = 0; k < 16; ++k) tot += rr[k][t];
    pool[t] = tot * (1.0f/65536.0f);
  }
  __syncthreads();
  if (t < 16){
    float pm = (t > 0)  ? pool[t-1] : 0.f;
    float p0 = pool[t];
    float pp = (t < 15) ? pool[t+1] : 0.f;
    float z = Weca[0]*pm + Weca[1]*p0 + Weca[2]*pp;
    gate[b*16 + t] = 1.f/(1.f + __expf(-z));
  }
}

// K5: out = x * gate[b,c], nontemporal stores
__global__ __launch_bounds__(256) void k5_scale(
    const f32x4* __restrict__ x4, const float* __restrict__ gate,
    f32x4* __restrict__ out4)
{
  int idx = blockIdx.x*256 + threadIdx.x;
  float g = gate[idx >> 14];
  f32x4 v = x4[idx] * g;
  __builtin_nontemporal_store(v, &out4[idx]);
}

extern "C" void kernel_launch(void* const* d_in, const int* in_sizes, int n_in,
                              void* d_out, int out_size, void* d_ws, size_t ws_size,
                              hipStream_t stream)
{
  const float* x     = (const float*)d_in[0];
  const float* W1    = (const float*)d_in[1];
  const float* b1    = (const float*)d_in[2];
  const float* Wred  = (const float*)d_in[3];
  const float* bred  = (const float*)d_in[4];
  const float* Wspan = (const float*)d_in[5];
  const float* bspan = (const float*)d_in[6];
  const float* W2    = (const float*)d_in[7];
  const float* b2    = (const float*)d_in[8];
  const float* Weca  = (const float*)d_in[9];

  ushort_t* shuf    = (ushort_t*)d_ws;                        // 64 MiB records
  float*    gate    = (float*)((char*)d_ws + 67108864);       // 512 B
  ushort_t* wpack   = (ushort_t*)((char*)d_ws + 67108864 + 1024); // 18.4 KiB
  float*    scratch = (float*)d_out;  // 2048*16 floats; overwritten by k5

  k0_pack<<<9, 128, 0, stream>>>(W2, wpack);
  k12    <<<4096, 256, 0, stream>>>(x, W1, b1, Wred, bred, Wspan, bspan, shuf);
  k3_conv2<<<2048, 256, 0, stream>>>(shuf, wpack, b2, scratch);
  k4_gate<<<8, 256, 0, stream>>>(scratch, Weca, gate);
  k5_scale<<<8192, 256, 0, stream>>>((const f32x4*)x, gate, (f32x4*)d_out);
}

// Round 8
// 84.955 us; speedup vs baseline: 3.8800x; 1.0058x over previous
//
#include <hip/hip_runtime.h>
#include <hip/hip_bf16.h>

#define H 256
#define Wd 256
#define H2 128

typedef unsigned short ushort_t;
typedef __attribute__((ext_vector_type(8))) short short8;
typedef __attribute__((ext_vector_type(4))) float f32x4;
typedef __attribute__((ext_vector_type(2))) float f32x2;

__device__ __forceinline__ float mishf(float v){
  if (v > 15.f) return v;
  float e = __expf(v);
  float w = e*(e+2.f);
  return v * w * __builtin_amdgcn_rcpf(w + 2.f);
}

__device__ __forceinline__ ushort_t f2bf(float f){
  unsigned int u = __float_as_uint(f);
  u += 0x7fffu + ((u >> 16) & 1u);
  return (ushort_t)(u >> 16);
}
__device__ __forceinline__ float bf2f(ushort_t h){
  return __uint_as_float(((unsigned int)h) << 16);
}
__device__ __forceinline__ unsigned packbf(float a, float b){
  return (unsigned)f2bf(a) | ((unsigned)f2bf(b) << 16);
}
__device__ __forceinline__ float lo16(unsigned u){
  return __uint_as_float(u << 16);
}
__device__ __forceinline__ float hi16(unsigned u){
  return __uint_as_float(u & 0xffff0000u);
}

// All-pair VOP3P FMAs. acc.{lo,hi} += f.{lo,hi} * broadcast(w.lo or w.hi).
// op_sel picks the half read by the LOW result lane, op_sel_hi by the HIGH.
__device__ __forceinline__ void pk_lo(f32x2 &acc, f32x2 f, f32x2 w){
  asm("v_pk_fma_f32 %0, %1, %2, %0 op_sel_hi:[1,0,1]"
      : "+v"(acc) : "v"(f), "v"(w));
}
__device__ __forceinline__ void pk_hi(f32x2 &acc, f32x2 f, f32x2 w){
  asm("v_pk_fma_f32 %0, %1, %2, %0 op_sel:[0,1,0] op_sel_hi:[1,1,1]"
      : "+v"(acc) : "v"(f), "v"(w));
}

// ---------------------------------------------------------------------------
// shuf layout: 8-byte pixel records  [plane = b*16 + c][i*256 + j][m0..3]
// (bf16 x4). k12 writes top rows (own plane) and bottom rows (rolled plane).
// ---------------------------------------------------------------------------

// K0: pre-pack W2 into bf16 MFMA A-fragment order.
__global__ void k0_pack(const float* __restrict__ W2, ushort_t* __restrict__ wpack)
{
  int idx = blockIdx.x*128 + threadIdx.x;   // 0..1151
  if (idx >= 1152) return;
  int lane  = idx & 63;
  int s     = (idx >> 6) % 9;
  int khalf = idx / 576;
  int n = lane & 15, g = lane >> 4;
  unsigned int w[4];
#pragma unroll
  for (int h = 0; h < 4; ++h){
    int ch0 = khalf*32 + g*8 + 2*h;
    unsigned lo = f2bf(W2[(n*64 + ch0  )*9 + s]);
    unsigned hi = f2bf(W2[(n*64 + ch0+1)*9 + s]);
    w[h] = lo | (hi << 16);
  }
  *(uint4*)(wpack + (size_t)idx*8) = make_uint4(w[0], w[1], w[2], w[3]);
}

// ---------------------------------------------------------------------------
// K12: fused conv1 top+bottom for one (plane, 16x64 tile).
// All inner products via guaranteed v_pk_fma_f32 (pair operands + op_sel
// broadcast of the weight half). ft phase & f_bot: pixel-pair accumulation;
// span phase: m-pair (packed-bf16 word unpacks straight into the pair).
// ---------------------------------------------------------------------------
__global__ __launch_bounds__(256,4) void k12(
    const float* __restrict__ x, const float* __restrict__ W1,
    const float* __restrict__ b1, const float* __restrict__ Wred,
    const float* __restrict__ bred, const float* __restrict__ Wspan,
    const float* __restrict__ bspan, ushort_t* __restrict__ shuf)
{
  __shared__ float xt[20][71];       // x rows itop0-2..+17, cols j0-4..j0+66
  __shared__ float xb[18][71];       // x rows 127+itop0..+17, cols j0-4..j0+66
  __shared__ unsigned ftp[2][18][67];// packed bf16 (m0|m1),(m2|m3)

  int bid = blockIdx.x;             // 128 planes * 8 rowtiles * 4 coltiles
  int n   = bid >> 5;
  int t   = bid & 31;
  int itop0 = (t >> 2) * 16;
  int j0    = (t & 3) * 64;
  int tid = threadIdx.x;
  const float* xp = x + (size_t)n * (H*Wd);

  f32x2 w01[9], w23[9], wspb[9];
  f32x2 bsp0, bsp1, bsp2, bsp3;
  float wredr[4];
  float bredr = bred[0];
#pragma unroll
  for (int k=0;k<9;k++){
    w01[k] = f32x2{W1[k], W1[9+k]};
    w23[k] = f32x2{W1[18+k], W1[27+k]};
    wspb[k] = f32x2{Wspan[k], bspan[k]};
  }
  bsp0 = f32x2{b1[0], b1[0]};
  bsp1 = f32x2{b1[1], b1[1]};
  bsp2 = f32x2{b1[2], b1[2]};
  bsp3 = f32x2{b1[3], b1[3]};
#pragma unroll
  for (int m=0;m<4;m++) wredr[m] = Wred[m];

  // ---- stage x_top: 20 rows x 18 float4 (cols j0-4 .. j0+67) ----
  for (int idx=tid; idx<360; idx+=256){
    int r = idx/18, q = idx - r*18;
    int grow = itop0-2+r, gcol = j0-4+q*4;
    float4 v = make_float4(0.f,0.f,0.f,0.f);
    if (grow>=0 && gcol>=0 && gcol<Wd)
      v = *(const float4*)(xp + (size_t)grow*Wd + gcol);
    int c0 = q*4;
    xt[r][c0] = v.x; xt[r][c0+1] = v.y; xt[r][c0+2] = v.z;
    if (c0+3 < 71) xt[r][c0+3] = v.w;
  }
  // ---- stage x_bot: 18 rows x 18 float4 ----
  for (int idx=tid; idx<324; idx+=256){
    int r = idx/18, q = idx - r*18;
    int grow = 127+itop0+r, gcol = j0-4+q*4;
    float4 v = make_float4(0.f,0.f,0.f,0.f);
    if (grow<H && gcol>=0 && gcol<Wd)
      v = *(const float4*)(xp + (size_t)grow*Wd + gcol);
    int c0 = q*4;
    xb[r][c0] = v.x; xb[r][c0+1] = v.y; xb[r][c0+2] = v.z;
    if (c0+3 < 71) xb[r][c0+3] = v.w;
  }
  __syncthreads();

  // ---- f_top -> packed bf16 LDS; pixel-pair accumulation (18 x 33 pairs) ----
  for (int idx=tid; idx<594; idx+=256){
    int r = idx/33, cp = idx - r*33;
    int c = cp*2;                   // elem col in [0,66)
    f32x2 sm0=bsp0, sm1=bsp1, sm2=bsp2, sm3=bsp3;
#pragma unroll
    for (int ky=0;ky<3;ky++){
      float x0 = xt[r+ky][c+2], x1 = xt[r+ky][c+3];
      float x2 = xt[r+ky][c+4], x3 = xt[r+ky][c+5];
      f32x2 p0 = f32x2{x0,x1}, p1 = f32x2{x1,x2}, p2 = f32x2{x2,x3};
      f32x2 wa0 = w01[ky*3], wa1 = w01[ky*3+1], wa2 = w01[ky*3+2];
      f32x2 wb0 = w23[ky*3], wb1 = w23[ky*3+1], wb2 = w23[ky*3+2];
      pk_lo(sm0,p0,wa0); pk_hi(sm1,p0,wa0); pk_lo(sm2,p0,wb0); pk_hi(sm3,p0,wb0);
      pk_lo(sm0,p1,wa1); pk_hi(sm1,p1,wa1); pk_lo(sm2,p1,wb1); pk_hi(sm3,p1,wb1);
      pk_lo(sm0,p2,wa2); pk_hi(sm1,p2,wa2); pk_lo(sm2,p2,wb2); pk_hi(sm3,p2,wb2);
    }
    int frow = itop0-1+r;
    int fc0  = j0-1+c;
    bool rok = (frow>=0) && (frow<H2);
    bool ok0 = rok && (fc0>=0) && (fc0<Wd);
    bool ok1 = rok && (fc0+1<Wd);
    ftp[0][r][c]   = ok0 ? packbf(mishf(sm0.x), mishf(sm1.x)) : 0u;
    ftp[1][r][c]   = ok0 ? packbf(mishf(sm2.x), mishf(sm3.x)) : 0u;
    ftp[0][r][c+1] = ok1 ? packbf(mishf(sm0.y), mishf(sm1.y)) : 0u;
    ftp[1][r][c+1] = ok1 ? packbf(mishf(sm2.y), mishf(sm3.y)) : 0u;
  }

  int lr  = tid >> 4;
  int lc4 = (tid & 15) * 4;
  int trow = itop0 + lr;
  int bq = n >> 4, cq = n & 15;

  // ---- f_bot own 4 px, pixel-pair: sA* = px(0,1), sB* = px(2,3) ----
  f32x2 xq[3][5];
#pragma unroll
  for (int r=0;r<3;r++)
#pragma unroll
    for (int c2=0;c2<5;c2++)
      xq[r][c2] = f32x2{xb[lr+r][lc4+3+c2], xb[lr+r][lc4+4+c2]};

  f32x2 sA0=bsp0,sA1=bsp1,sA2=bsp2,sA3=bsp3;
  f32x2 sB0=bsp0,sB1=bsp1,sB2=bsp2,sB3=bsp3;
#pragma unroll
  for (int ky=0;ky<3;ky++)
#pragma unroll
    for (int kx=0;kx<3;kx++){
      f32x2 w0 = w01[ky*3+kx], w2 = w23[ky*3+kx];
      f32x2 qa = xq[ky][kx], qb = xq[ky][kx+2];
      pk_lo(sA0, qa, w0); pk_hi(sA1, qa, w0);
      pk_lo(sA2, qa, w2); pk_hi(sA3, qa, w2);
      pk_lo(sB0, qb, w0); pk_hi(sB1, qb, w0);
      pk_lo(sB2, qb, w2); pk_hi(sB3, qb, w2);
    }
  float fb[4][4];
  fb[0][0]=mishf(sA0.x); fb[0][1]=mishf(sA0.y); fb[0][2]=mishf(sB0.x); fb[0][3]=mishf(sB0.y);
  fb[1][0]=mishf(sA1.x); fb[1][1]=mishf(sA1.y); fb[1][2]=mishf(sB1.x); fb[1][3]=mishf(sB1.y);
  fb[2][0]=mishf(sA2.x); fb[2][1]=mishf(sA2.y); fb[2][2]=mishf(sB2.x); fb[2][3]=mishf(sB2.y);
  fb[3][0]=mishf(sA3.x); fb[3][1]=mishf(sA3.y); fb[3][2]=mishf(sB3.x); fb[3][3]=mishf(sB3.y);

  // bottom store (rolled plane), 2 px per dwordx4
  int cdst = (cq + 15) & 15;
  size_t bbase = ((size_t)(bq*16 + cdst))*65536 + (size_t)(128+trow)*256 + j0 + lc4;
  {
    unsigned w0 = packbf(fb[0][0], fb[1][0]), w1 = packbf(fb[2][0], fb[3][0]);
    unsigned w2 = packbf(fb[0][1], fb[1][1]), w3 = packbf(fb[2][1], fb[3][1]);
    *(uint4*)(shuf + bbase*4) = make_uint4(w0,w1,w2,w3);
    unsigned w4 = packbf(fb[0][2], fb[1][2]), w5 = packbf(fb[2][2], fb[3][2]);
    unsigned w6 = packbf(fb[0][3], fb[1][3]), w7 = packbf(fb[2][3], fb[3][3]);
    *(uint4*)(shuf + (bbase+2)*4) = make_uint4(w4,w5,w6,w7);
  }
  float gv[4];
#pragma unroll
  for (int p=0;p<4;p++){
    float s = bredr;
#pragma unroll
    for (int m=0;m<4;m++) s = fmaf(fb[m][p], wredr[m], s);
    gv[p] = fmaxf(s, 0.f);
  }

  __syncthreads();

  // ---- span convs: m-pair accumulation straight from packed words ----
  f32x2 pA01[4], pB01[4], pA23[4], pB23[4];
#pragma unroll
  for (int p=0;p<4;p++){
    pA01[p] = f32x2{0.f,0.f}; pB01[p] = f32x2{0.f,0.f};
    pA23[p] = f32x2{0.f,0.f}; pB23[p] = f32x2{0.f,0.f};
  }
#pragma unroll
  for (int ky=0;ky<3;ky++){
    f32x2 fm01[6], fm23[6];
#pragma unroll
    for (int c2=0;c2<6;c2++){
      unsigned u0 = ftp[0][lr+ky][lc4+c2];
      unsigned u1 = ftp[1][lr+ky][lc4+c2];
      fm01[c2] = f32x2{lo16(u0), hi16(u0)};
      fm23[c2] = f32x2{lo16(u1), hi16(u1)};
    }
#pragma unroll
    for (int kx=0;kx<3;kx++){
      f32x2 w = wspb[ky*3+kx];
#pragma unroll
      for (int p=0;p<4;p++){
        pk_lo(pA01[p], fm01[p+kx], w);
        pk_hi(pB01[p], fm01[p+kx], w);
        pk_lo(pA23[p], fm23[p+kx], w);
        pk_hi(pB23[p], fm23[p+kx], w);
      }
    }
  }
  float o[4][4];
#pragma unroll
  for (int p=0;p<4;p++){
    o[0][p] = fmaf(gv[p], pA01[p].x, pB01[p].x);
    o[1][p] = fmaf(gv[p], pA01[p].y, pB01[p].y);
    o[2][p] = fmaf(gv[p], pA23[p].x, pB23[p].x);
    o[3][p] = fmaf(gv[p], pA23[p].y, pB23[p].y);
  }
  size_t pbase = ((size_t)(bq*16 + cq))*65536 + (size_t)trow*256 + j0 + lc4;
  {
    unsigned w0 = packbf(o[0][0], o[1][0]), w1 = packbf(o[2][0], o[3][0]);
    unsigned w2 = packbf(o[0][1], o[1][1]), w3 = packbf(o[2][1], o[3][1]);
    *(uint4*)(shuf + pbase*4) = make_uint4(w0,w1,w2,w3);
    unsigned w4 = packbf(o[0][2], o[1][2]), w5 = packbf(o[2][2], o[3][2]);
    unsigned w6 = packbf(o[0][3], o[1][3]), w7 = packbf(o[2][3], o[3][3]);
    *(uint4*)(shuf + (pbase+2)*4) = make_uint4(w4,w5,w6,w7);
  }
}

// ---------------------------------------------------------------------------
// K3: conv2 via MFMA implicit GEMM, direct-from-global B fragments.
// ---------------------------------------------------------------------------
__global__ __launch_bounds__(256) void k3_conv2(
    const ushort_t* __restrict__ shuf, const ushort_t* __restrict__ wpack,
    const float* __restrict__ b2, float* __restrict__ scratch)
{
  __shared__ f32x4 mg[2][8][64];   // 16 KiB
  __shared__ float pacc[16];

  int bid0 = blockIdx.x;                     // 2048
  int bid  = (bid0 & 7)*256 + (bid0 >> 3);   // XCD-contiguous chunks
  int b   = bid >> 8;
  int t   = bid & 255;
  int rb  = t >> 3;
  int cb  = t & 7;
  int tid = threadIdx.x;
  int lane = tid & 63;
  int n = lane & 15;
  int g = lane >> 4;
  int wid = tid >> 6;
  int colhalf = wid & 1;
  int khalf   = wid >> 1;

  if (tid < 16) pacc[tid] = 0.f;

  const short8* wp = (const short8*)wpack + (size_t)khalf*576 + lane;
  short8 afr[9];
#pragma unroll
  for (int s = 0; s < 9; ++s) afr[s] = wp[s*64];

  f32x4 acc[8];
#pragma unroll
  for (int r = 0; r < 8; ++r) acc[r] = f32x4{0.f,0.f,0.f,0.f};

  int r0 = rb*8 - 1;
  int c  = cb*32 - 1 + colhalf*16 + n;
  int p0 = khalf*8 + g*2;
  const ushort_t* sp = shuf + ((size_t)(b*16 + p0))*262144;

#pragma unroll
  for (int hr = 0; hr < 10; ++hr){
    int grow = r0 + hr;
    bool rok = (unsigned)grow < 256u;
    uint2 va[3], vb[3];
#pragma unroll
    for (int kx = 0; kx < 3; ++kx){
      int gcol = c + kx;
      uint2 a = make_uint2(0u,0u), bv = make_uint2(0u,0u);
      if (rok && (unsigned)gcol < 256u){
        const ushort_t* pp = sp + (size_t)(grow*256 + gcol)*4;
        a  = *(const uint2*)pp;
        bv = *(const uint2*)(pp + 262144);
      }
      va[kx] = a; vb[kx] = bv;
    }
#pragma unroll
    for (int kx = 0; kx < 3; ++kx){
      union { uint4 u; short8 s; } cv;
      cv.u = make_uint4(va[kx].x, va[kx].y, vb[kx].x, vb[kx].y);
#pragma unroll
      for (int ky = 0; ky < 3; ++ky){
        int orow = hr - ky;
        if (orow >= 0 && orow < 8){
          acc[orow] = __builtin_amdgcn_mfma_f32_16x16x32_bf16(
              afr[ky*3+kx], cv.s, acc[orow], 0, 0, 0);
        }
      }
    }
  }

  if (khalf == 1){
#pragma unroll
    for (int r = 0; r < 8; ++r) mg[colhalf][r][lane] = acc[r];
  }
  __syncthreads();

  if (khalf == 0){
    float b2v[4];
#pragma unroll
    for (int q = 0; q < 4; ++q) b2v[q] = b2[g*4 + q];
    float po[4] = {0.f, 0.f, 0.f, 0.f};
#pragma unroll
    for (int r = 0; r < 8; ++r){
      f32x4 o = acc[r] + mg[colhalf][r][lane];
#pragma unroll
      for (int q = 0; q < 4; ++q) po[q] += mishf(o[q] + b2v[q]);
    }
#pragma unroll
    for (int q = 0; q < 4; ++q){
#pragma unroll
      for (int mk = 1; mk < 16; mk <<= 1) po[q] += __shfl_xor(po[q], mk);
    }
    if (n == 0){
#pragma unroll
      for (int q = 0; q < 4; ++q) atomicAdd(&pacc[g*4 + q], po[q]);
    }
  }
  __syncthreads();
  if (tid < 16) scratch[bid*16 + tid] = pacc[tid];
}

// K4: reduce per-block partials -> pooled mean -> ECA gate. One block per b.
__global__ void k4_gate(const float* __restrict__ scratch,
                        const float* __restrict__ Weca,
                        float* __restrict__ gate)
{
  __shared__ float rr[16][16];
  __shared__ float pool[16];
  int b = blockIdx.x;
  int t = threadIdx.x;           // 256
  int oc = t & 15, ch = t >> 4;
  float s = 0.f;
  for (int u = 0; u < 16; ++u)
    s += scratch[(size_t)(b*256 + ch*16 + u)*16 + oc];
  rr[ch][oc] = s;
  __syncthreads();
  if (t < 16){
    float tot = 0.f;
#pragma unroll
    for (int k = 0; k < 16; ++k) tot += rr[k][t];
    pool[t] = tot * (1.0f/65536.0f);
  }
  __syncthreads();
  if (t < 16){
    float pm = (t > 0)  ? pool[t-1] : 0.f;
    float p0 = pool[t];
    float pp = (t < 15) ? pool[t+1] : 0.f;
    float z = Weca[0]*pm + Weca[1]*p0 + Weca[2]*pp;
    gate[b*16 + t] = 1.f/(1.f + __expf(-z));
  }
}

// K5: out = x * gate[b,c], nontemporal stores
__global__ __launch_bounds__(256) void k5_scale(
    const f32x4* __restrict__ x4, const float* __restrict__ gate,
    f32x4* __restrict__ out4)
{
  int idx = blockIdx.x*256 + threadIdx.x;
  float g = gate[idx >> 14];
  f32x4 v = x4[idx] * g;
  __builtin_nontemporal_store(v, &out4[idx]);
}

extern "C" void kernel_launch(void* const* d_in, const int* in_sizes, int n_in,
                              void* d_out, int out_size, void* d_ws, size_t ws_size,
                              hipStream_t stream)
{
  const float* x     = (const float*)d_in[0];
  const float* W1    = (const float*)d_in[1];
  const float* b1    = (const float*)d_in[2];
  const float* Wred  = (const float*)d_in[3];
  const float* bred  = (const float*)d_in[4];
  const float* Wspan = (const float*)d_in[5];
  const float* bspan = (const float*)d_in[6];
  const float* W2    = (const float*)d_in[7];
  const float* b2    = (const float*)d_in[8];
  const float* Weca  = (const float*)d_in[9];

  ushort_t* shuf    = (ushort_t*)d_ws;                        // 64 MiB records
  float*    gate    = (float*)((char*)d_ws + 67108864);       // 512 B
  ushort_t* wpack   = (ushort_t*)((char*)d_ws + 67108864 + 1024); // 18.4 KiB
  float*    scratch = (float*)d_out;  // 2048*16 floats; overwritten by k5

  k0_pack<<<9, 128, 0, stream>>>(W2, wpack);
  k12    <<<4096, 256, 0, stream>>>(x, W1, b1, Wred, bred, Wspan, bspan, shuf);
  k3_conv2<<<2048, 256, 0, stream>>>(shuf, wpack, b2, scratch);
  k4_gate<<<8, 256, 0, stream>>>(scratch, Weca, gate);
  k5_scale<<<8192, 256, 0, stream>>>((const f32x4*)x, gate, (f32x4*)d_out);
}